// Round 1
// baseline (1024.723 us; speedup 1.0000x reference)
//
#include <hip/hip_runtime.h>
#include <hip/hip_bf16.h>
#include <stdint.h>
#include <stddef.h>

using bf16 = __hip_bfloat16;
typedef __bf16 bf16x8 __attribute__((ext_vector_type(8)));
typedef float f32x4 __attribute__((ext_vector_type(4)));

#define P_  16384
#define NH_ 64
#define NN_ 256

// ---------------------------------------------------------------- async g->LDS
__device__ __forceinline__ void gload16(const void* g, void* l) {
    __builtin_amdgcn_global_load_lds((const __attribute__((address_space(1))) void*)g,
                                     (__attribute__((address_space(3))) void*)l, 16, 0, 0);
}

// ---------------------------------------------------------------- GEMM (B^T)
// C[M,N] = A[M,K] @ B^T where B is stored N x K row-major (both bf16).
// 128x128 tile, BK=32, 4 waves in 2x2, each wave 4x4 frags of 16x16x32 MFMA.
template<bool RELU, bool BIAS, bool OBF>
__global__ __launch_bounds__(256, 3)
void gemm_bt(const bf16* __restrict__ A, const bf16* __restrict__ B,
             void* __restrict__ C, const float* __restrict__ bias,
             int M, int N, int K, int ldc)
{
    __shared__ __align__(16) bf16 As[128 * 32];
    __shared__ __align__(16) bf16 Bs[128 * 32];

    const int tid  = threadIdx.x;
    const int wave = tid >> 6;
    const int lane = tid & 63;
    const int tileM = blockIdx.x * 128;
    const int tileN = blockIdx.y * 128;
    const int wr = (wave >> 1) << 6;   // wave row offset in tile
    const int wc = (wave & 1) << 6;    // wave col offset in tile

    f32x4 acc[4][4] = {};

    int arow[2], brow[2], ako[2];
    #pragma unroll
    for (int j = 0; j < 2; ++j) {
        int c  = wave * 128 + j * 64 + lane;   // chunk id 0..511
        int r  = c >> 2;                        // tile row 0..127
        ako[j] = (c & 3) << 3;                  // k offset 0/8/16/24
        int gr = tileM + r; if (gr > M - 1) gr = M - 1;
        arow[j] = gr;
        int gn = tileN + r; if (gn > N - 1) gn = N - 1;
        brow[j] = gn;
    }
    const int m0   = wr + (lane & 15);
    const int n0   = wc + (lane & 15);
    const int koff = (lane >> 4) << 3;

    for (int k0 = 0; k0 < K; k0 += 32) {
        #pragma unroll
        for (int j = 0; j < 2; ++j) {
            int c = wave * 128 + j * 64 + lane;
            gload16(A + (size_t)arow[j] * K + k0 + ako[j], (void*)(As + c * 8));
            gload16(B + (size_t)brow[j] * K + k0 + ako[j], (void*)(Bs + c * 8));
        }
        __syncthreads();
        bf16x8 af[4], bfv[4];
        #pragma unroll
        for (int i = 0; i < 4; ++i) {
            af[i]  = *(const bf16x8*)(As + (m0 + i * 16) * 32 + koff);
            bfv[i] = *(const bf16x8*)(Bs + (n0 + i * 16) * 32 + koff);
        }
        #pragma unroll
        for (int i = 0; i < 4; ++i)
            #pragma unroll
            for (int j = 0; j < 4; ++j)
                acc[i][j] = __builtin_amdgcn_mfma_f32_16x16x32_bf16(af[i], bfv[j], acc[i][j], 0, 0, 0);
        __syncthreads();
    }

    const int rbase = tileM + wr + ((lane >> 4) << 2);
    const int cbase = tileN + wc + (lane & 15);
    #pragma unroll
    for (int i = 0; i < 4; ++i)
        #pragma unroll
        for (int j = 0; j < 4; ++j)
            #pragma unroll
            for (int r = 0; r < 4; ++r) {
                int grow = rbase + i * 16 + r;
                if (grow >= M) continue;
                int gcol = cbase + j * 16;
                float v = acc[i][j][r];
                if (BIAS) v += bias[gcol];
                if (RELU) v = fmaxf(v, 0.f);
                if (OBF)  ((bf16*)C)[(size_t)grow * ldc + gcol] = __float2bfloat16(v);
                else      ((float*)C)[(size_t)grow * ldc + gcol] = v;
            }
}

static void run_gemm(hipStream_t st, const bf16* A, const bf16* B, void* C, const float* bias,
                     int M, int N, int K, int ldc, bool relu, bool obf)
{
    dim3 g((M + 127) / 128, N / 128), b(256);
    if (obf) {
        if (relu)           gemm_bt<true,  true,  true ><<<g, b, 0, st>>>(A, B, C, bias, M, N, K, ldc);
        else if (bias)      gemm_bt<false, true,  true ><<<g, b, 0, st>>>(A, B, C, bias, M, N, K, ldc);
        else                gemm_bt<false, false, true ><<<g, b, 0, st>>>(A, B, C, bias, M, N, K, ldc);
    } else {
        if (relu)           gemm_bt<true,  true,  false><<<g, b, 0, st>>>(A, B, C, bias, M, N, K, ldc);
        else if (bias)      gemm_bt<false, true,  false><<<g, b, 0, st>>>(A, B, C, bias, M, N, K, ldc);
        else                gemm_bt<false, false, false><<<g, b, 0, st>>>(A, B, C, bias, M, N, K, ldc);
    }
}

// ---------------------------------------------------------------- converters
// batched transpose: dst[z][c*rows + r] = bf16(src[z][r*cols + c])
__global__ void transp(const float* __restrict__ src, bf16* __restrict__ dst,
                       int rows, int cols, size_t sstride, size_t dstride)
{
    const float* s = src + blockIdx.z * sstride;
    bf16*        d = dst + blockIdx.z * dstride;
    __shared__ float tile[32][33];
    int c0 = blockIdx.x * 32, r0 = blockIdx.y * 32;
    int x = threadIdx.x, y = threadIdx.y;   // (32, 8)
    for (int yy = y; yy < 32; yy += 8) {
        int r = r0 + yy, c = c0 + x;
        tile[yy][x] = (r < rows && c < cols) ? s[(size_t)r * cols + c] : 0.f;
    }
    __syncthreads();
    for (int yy = y; yy < 32; yy += 8) {
        int c = c0 + yy, r = r0 + x;
        if (c < cols && r < rows) d[(size_t)c * rows + r] = __float2bfloat16(tile[x][yy]);
    }
}

__global__ void conv_spw1(const float* __restrict__ src, bf16* __restrict__ dst) {
    int i = blockIdx.x * 256 + threadIdx.x;        // 128*64 (B^T padded K 36->64)
    if (i >= 128 * 64) return;
    int k = i & 63, n = i >> 6;
    dst[i] = __float2bfloat16(k < 36 ? src[k * 128 + n] : 0.f);
}

__global__ void pad_spatial(const float* __restrict__ src, bf16* __restrict__ dst) {
    int i = blockIdx.x * 256 + threadIdx.x;        // P*64
    int k = i & 63, p = i >> 6;
    dst[i] = __float2bfloat16(k < 36 ? src[p * 36 + k] : 0.f);
}

__global__ void cast_f2b(const float* __restrict__ src, bf16* __restrict__ dst, int n) {
    int i = blockIdx.x * 256 + threadIdx.x;
    if (i < n) dst[i] = __float2bfloat16(src[i]);
}

__global__ void sumb3_k(const float* __restrict__ b3, float* __restrict__ out) {
    int r = blockIdx.x * 256 + threadIdx.x;        // 1024
    float s = 0.f;
    #pragma unroll
    for (int c = 0; c < 16; ++c) s += b3[c * 1024 + r];
    out[r] = s;
}

// ---------------------------------------------------------------- H builders
// mode 0: a1 = Ah[p>>8] + Ao[p&255] + b1 ; 1: a1 = A1a[p&255] ; 2: a1 = A1a[p>>8] ; 3: a1 = A1a (vector)
__global__ void hbuild(const float* __restrict__ A1a, const float* __restrict__ A1b,
                       const float* __restrict__ b1, const bf16* __restrict__ a2,
                       bf16* __restrict__ H, int mode)
{
    size_t base = ((size_t)blockIdx.x * 256 + threadIdx.x) * 8;
    int cs = (int)(base & 1023);
    int p  = (int)(base >> 10);
    float a1[8];
    if (mode == 0) {
        const float* ph = A1a + ((size_t)(p >> 8) << 10) + cs;
        const float* po = A1b + ((size_t)(p & 255) << 10) + cs;
        #pragma unroll
        for (int j = 0; j < 8; ++j) a1[j] = ph[j] + po[j] + b1[cs + j];
    } else if (mode == 1) {
        const float* pa = A1a + ((size_t)(p & 255) << 10) + cs;
        #pragma unroll
        for (int j = 0; j < 8; ++j) a1[j] = pa[j];
    } else if (mode == 2) {
        const float* pa = A1a + ((size_t)(p >> 8) << 10) + cs;
        #pragma unroll
        for (int j = 0; j < 8; ++j) a1[j] = pa[j];
    } else {
        #pragma unroll
        for (int j = 0; j < 8; ++j) a1[j] = A1a[cs + j];
    }
    bf16x8 av = *(const bf16x8*)(a2 + base);
    bf16x8 o;
    #pragma unroll
    for (int j = 0; j < 8; ++j) {
        float v = a1[j] * (float)av[j];
        o[j] = (__bf16)fmaxf(v, 0.f);
    }
    *(bf16x8*)(H + base) = o;
}

// ---------------------------------------------------------------- adj / softmax / msg / LN
__global__ void adj_dot(const float* __restrict__ W, const float* __restrict__ adjW,
                        const float* __restrict__ adjb, float* __restrict__ adj)
{
    int p = blockIdx.x * 4 + (threadIdx.x >> 6);
    int lane = threadIdx.x & 63;
    const float* row = W + (size_t)p * 1024;
    float s = 0.f;
    #pragma unroll
    for (int k = 0; k < 16; ++k) { int r = lane + k * 64; s += row[r] * adjW[r]; }
    #pragma unroll
    for (int off = 32; off; off >>= 1) s += __shfl_down(s, off);
    if (lane == 0) adj[p] = s + adjb[0];
}

__global__ void softmax_h(const float* __restrict__ adj, float* __restrict__ sh) {
    int h = blockIdx.x, n = threadIdx.x;           // 64 blocks x 256
    __shared__ float red[256];
    float v = adj[h * 256 + n];
    red[n] = v; __syncthreads();
    for (int s = 128; s > 0; s >>= 1) { if (n < s) red[n] = fmaxf(red[n], red[n + s]); __syncthreads(); }
    float m = red[0]; __syncthreads();
    float e = expf(v - m);
    red[n] = e; __syncthreads();
    for (int s = 128; s > 0; s >>= 1) { if (n < s) red[n] += red[n + s]; __syncthreads(); }
    sh[h * 256 + n] = e / red[0];
}

__global__ void softmax_o(const float* __restrict__ adj, float* __restrict__ so) {
    int n = blockIdx.x, h = threadIdx.x;           // 256 blocks x 64 (one wave)
    float v = adj[h * 256 + n];
    float m = v;
    #pragma unroll
    for (int off = 32; off; off >>= 1) m = fmaxf(m, __shfl_xor(m, off));
    float e = expf(v - m);
    float s = e;
    #pragma unroll
    for (int off = 32; off; off >>= 1) s += __shfl_xor(s, off);
    so[n * 64 + h] = e / s;
}

__global__ void msgh_k(const float* __restrict__ M, const float* __restrict__ sh,
                       const float* __restrict__ sb3, float* __restrict__ msg)
{
    int h = blockIdx.x;                            // (64, 4) x 256
    int r = blockIdx.y * 256 + threadIdx.x;
    const float* base = M + (size_t)h * 256 * 1024 + r;
    const float* w = sh + h * 256;
    float acc = 0.f;
    #pragma unroll 4
    for (int n = 0; n < 256; ++n) acc += w[n] * base[(size_t)n * 1024];
    msg[h * 1024 + r] = fmaxf(acc + sb3[r], 0.f);
}

__global__ void msgo_k(const float* __restrict__ M, const float* __restrict__ so,
                       const float* __restrict__ sb3, float* __restrict__ msg)
{
    int n = blockIdx.x;                            // (256, 4) x 256
    int r = blockIdx.y * 256 + threadIdx.x;
    const float* w = so + n * 64;
    float acc = 0.f;
    #pragma unroll 4
    for (int h = 0; h < 64; ++h) acc += w[h] * M[((size_t)h * 256 + n) * 1024 + r];
    msg[n * 1024 + r] = fmaxf(acc + sb3[r], 0.f);
}

__global__ void ln_k(const float* __restrict__ x, const float* __restrict__ msg,
                     const float* __restrict__ g, const float* __restrict__ bb,
                     bf16* __restrict__ out)
{
    int row = blockIdx.x, t = threadIdx.x;         // rows x 256, E=1024
    const float* xr = x + (size_t)row * 1024;
    const float* mr = msg + (size_t)row * 1024;
    float v[4]; float s = 0.f, ss = 0.f;
    #pragma unroll
    for (int j = 0; j < 4; ++j) { int i = t + j * 256; v[j] = xr[i] + mr[i]; s += v[j]; ss += v[j] * v[j]; }
    __shared__ float r1[256], r2[256];
    r1[t] = s; r2[t] = ss; __syncthreads();
    for (int k = 128; k > 0; k >>= 1) { if (t < k) { r1[t] += r1[t + k]; r2[t] += r2[t + k]; } __syncthreads(); }
    float mean = r1[0] * (1.f / 1024.f);
    float var  = r2[0] * (1.f / 1024.f) - mean * mean;
    float inv  = rsqrtf(var + 1e-5f);
    #pragma unroll
    for (int j = 0; j < 4; ++j) {
        int i = t + j * 256;
        out[(size_t)row * 1024 + i] = __float2bfloat16((v[j] - mean) * inv * g[i] + bb[i]);
    }
}

__global__ void a1g_k(const float* __restrict__ gf, const float* __restrict__ W1,
                      const float* __restrict__ b1, float* __restrict__ a1g)
{
    int cs = blockIdx.x * 256 + threadIdx.x;       // 1024
    int c = cs >> 6, s = cs & 63;
    float acc = b1[cs];
    for (int g = 0; g < 256; ++g) acc += gf[g] * W1[((size_t)c * 256 + g) * 64 + s];
    a1g[cs] = acc;
}

// ---------------------------------------------------------------- launch
extern "C" void kernel_launch(void* const* d_in, const int* in_sizes, int n_in,
                              void* d_out, int out_size, void* d_ws, size_t ws_size,
                              hipStream_t stream)
{
    const float* node_enc = (const float*)d_in[0];
    const float* spatial  = (const float*)d_in[1];
    const float* gfeat    = (const float*)d_in[2];
    const float* sp_W1 = (const float*)d_in[3];  const float* sp_b1 = (const float*)d_in[4];
    const float* sp_W2 = (const float*)d_in[5];  const float* sp_b2 = (const float*)d_in[6];
    const float* sp_W3 = (const float*)d_in[7];  const float* sp_b3 = (const float*)d_in[8];
    const float* ah_W1 = (const float*)d_in[9];  const float* ah_b1 = (const float*)d_in[10];
    const float* ah_W2 = (const float*)d_in[11]; const float* ah_b2 = (const float*)d_in[12];
    const float* ah_W3 = (const float*)d_in[13]; const float* ah_b3 = (const float*)d_in[14];
    const float* o2s_W1 = (const float*)d_in[15]; const float* o2s_b1 = (const float*)d_in[16];
    const float* o2s_W2 = (const float*)d_in[17]; const float* o2s_b2 = (const float*)d_in[18];
    const float* o2s_W3 = (const float*)d_in[19]; const float* o2s_b3 = (const float*)d_in[20];
    const float* s2o_W1 = (const float*)d_in[21]; const float* s2o_b1 = (const float*)d_in[22];
    const float* s2o_W2 = (const float*)d_in[23]; const float* s2o_b2 = (const float*)d_in[24];
    const float* s2o_W3 = (const float*)d_in[25]; const float* s2o_b3 = (const float*)d_in[26];
    const float* ahg_W1 = (const float*)d_in[27]; const float* ahg_b1 = (const float*)d_in[28];
    const float* ahg_W2 = (const float*)d_in[29]; const float* ahg_b2 = (const float*)d_in[30];
    const float* ahg_W3 = (const float*)d_in[31]; const float* ahg_b3 = (const float*)d_in[32];
    const float* adj_W = (const float*)d_in[33]; const float* adj_b = (const float*)d_in[34];
    const float* lnh_g = (const float*)d_in[35]; const float* lnh_b = (const float*)d_in[36];
    const float* lno_g = (const float*)d_in[37]; const float* lno_b = (const float*)d_in[38];

    char* w = (char*)d_ws;
    auto alloc = [&](size_t bytes) { char* p = w; w += (bytes + 255) & ~(size_t)255; return p; };
    bf16*  sp      = (bf16*)alloc((size_t)P_ * 1024 * 2);
    bf16*  a2_ah   = (bf16*)alloc((size_t)P_ * 1024 * 2);
    bf16*  Hbuf    = (bf16*)alloc((size_t)P_ * 1024 * 2);
    float* Mbuf    = (float*)alloc((size_t)P_ * 1024 * 4);
    bf16*  a2_tmp  = (bf16*)Mbuf;                     // alias: liveness-disjoint
    bf16*  spat_pad= (bf16*)alloc((size_t)P_ * 64 * 2);
    bf16*  spL1    = (bf16*)alloc((size_t)P_ * 128 * 2);
    bf16*  spL2    = (bf16*)alloc((size_t)P_ * 256 * 2);
    bf16*  enc_bf  = (bf16*)alloc(256 * 1024 * 2);
    bf16*  henc_bf = (bf16*)alloc(64 * 1024 * 2);
    bf16*  oenc_bf = (bf16*)alloc(256 * 1024 * 2);
    bf16*  spW1t   = (bf16*)alloc(128 * 64 * 2);
    bf16*  spW2t   = (bf16*)alloc(256 * 128 * 2);
    bf16*  spW3t   = (bf16*)alloc(1024 * 256 * 2);
    bf16*  ahW1tT  = (bf16*)alloc(1024 * 1024 * 2);
    bf16*  ahW1tB  = (bf16*)alloc(1024 * 1024 * 2);
    bf16*  ahW2t   = (bf16*)alloc(1024 * 1024 * 2);
    bf16*  ahW3t   = (bf16*)alloc(1024 * 1024 * 2);
    bf16*  o2sW1t  = (bf16*)alloc(1024 * 1024 * 2);
    bf16*  o2sW2t  = (bf16*)alloc(1024 * 1024 * 2);
    bf16*  o2sW3t  = (bf16*)alloc(1024 * 1024 * 2);
    bf16*  s2oW1t  = (bf16*)alloc(1024 * 1024 * 2);
    bf16*  s2oW2t  = (bf16*)alloc(1024 * 1024 * 2);
    bf16*  s2oW3t  = (bf16*)alloc(1024 * 1024 * 2);
    bf16*  ahgW2t  = (bf16*)alloc(1024 * 1024 * 2);
    bf16*  ahgW3t  = (bf16*)alloc(1024 * 1024 * 2);
    float* Ah    = (float*)alloc(64 * 1024 * 4);
    float* Ao    = (float*)alloc(256 * 1024 * 4);
    float* a1o2s = (float*)alloc(256 * 1024 * 4);
    float* a1s2o = (float*)alloc(64 * 1024 * 4);
    float* a1g   = (float*)alloc(1024 * 4);
    float* adjv  = (float*)alloc(P_ * 4);
    float* sh    = (float*)alloc(P_ * 4);
    float* so    = (float*)alloc(P_ * 4);
    float* msgh  = (float*)alloc(64 * 1024 * 4);
    float* msgo  = (float*)alloc(256 * 1024 * 4);
    float* sb3_ah  = (float*)alloc(4096);
    float* sb3_o2s = (float*)alloc(4096);
    float* sb3_s2o = (float*)alloc(4096);
    float* sb3_ahg = (float*)alloc(4096);

    dim3 tb(32, 8);
    // ---- weight conversions (fp32 -> bf16 B^T layouts)
    conv_spw1<<<32, 256, 0, stream>>>(sp_W1, spW1t);
    transp<<<dim3(8, 4, 1),  tb, 0, stream>>>(sp_W2, spW2t, 128, 256, 0, 0);
    transp<<<dim3(32, 8, 1), tb, 0, stream>>>(sp_W3, spW3t, 256, 1024, 0, 0);
    transp<<<dim3(2, 32, 16), tb, 0, stream>>>(ah_W1,                    ahW1tT, 1024, 64, (size_t)2048 * 64, (size_t)64 * 1024);
    transp<<<dim3(2, 32, 16), tb, 0, stream>>>(ah_W1 + (size_t)1024 * 64, ahW1tB, 1024, 64, (size_t)2048 * 64, (size_t)64 * 1024);
    transp<<<dim3(2, 32, 16), tb, 0, stream>>>(ah_W2,  ahW2t,  1024, 64, 65536, 65536);
    transp<<<dim3(2, 32, 16), tb, 0, stream>>>(o2s_W1, o2sW1t, 1024, 64, 65536, 65536);
    transp<<<dim3(2, 32, 16), tb, 0, stream>>>(o2s_W2, o2sW2t, 1024, 64, 65536, 65536);
    transp<<<dim3(2, 32, 16), tb, 0, stream>>>(s2o_W1, s2oW1t, 1024, 64, 65536, 65536);
    transp<<<dim3(2, 32, 16), tb, 0, stream>>>(s2o_W2, s2oW2t, 1024, 64, 65536, 65536);
    transp<<<dim3(2, 32, 16), tb, 0, stream>>>(ahg_W2, ahgW2t, 1024, 64, 65536, 65536);
    transp<<<dim3(32, 32, 1), tb, 0, stream>>>(ah_W3,  ahW3t,  1024, 1024, 0, 0);
    transp<<<dim3(32, 32, 1), tb, 0, stream>>>(o2s_W3, o2sW3t, 1024, 1024, 0, 0);
    transp<<<dim3(32, 32, 1), tb, 0, stream>>>(s2o_W3, s2oW3t, 1024, 1024, 0, 0);
    transp<<<dim3(32, 32, 1), tb, 0, stream>>>(ahg_W3, ahgW3t, 1024, 1024, 0, 0);
    pad_spatial<<<4096, 256, 0, stream>>>(spatial, spat_pad);
    cast_f2b<<<1024, 256, 0, stream>>>(node_enc, enc_bf, 256 * 1024);
    sumb3_k<<<4, 256, 0, stream>>>(ah_b3,  sb3_ah);
    sumb3_k<<<4, 256, 0, stream>>>(o2s_b3, sb3_o2s);
    sumb3_k<<<4, 256, 0, stream>>>(s2o_b3, sb3_s2o);
    sumb3_k<<<4, 256, 0, stream>>>(ahg_b3, sb3_ahg);

    // ---- sp MLP
    run_gemm(stream, spat_pad, spW1t, spL1, sp_b1, P_, 128, 64, 128,  true, true);
    run_gemm(stream, spL1,     spW2t, spL2, sp_b2, P_, 256, 128, 256, true, true);
    run_gemm(stream, spL2,     spW3t, sp,   sp_b3, P_, 1024, 256, 1024, true, true);

    // ---- a2_ah (shared by weights & f_local)
    run_gemm(stream, sp, ahW2t, a2_ah, ah_b2, P_, 1024, 1024, 1024, false, true);

    // ---- weights = relu(pair_head(app_pairs)), adj, softmaxes
    run_gemm(stream, enc_bf, ahW1tT, Ah, nullptr, 64,  1024, 1024, 1024, false, false);
    run_gemm(stream, enc_bf, ahW1tB, Ao, nullptr, 256, 1024, 1024, 1024, false, false);
    hbuild<<<8192, 256, 0, stream>>>(Ah, Ao, ah_b1, a2_ah, Hbuf, 0);
    run_gemm(stream, Hbuf, ahW3t, Mbuf, sb3_ah, P_, 1024, 1024, 1024, true, false);
    adj_dot<<<4096, 256, 0, stream>>>(Mbuf, adj_W, adj_b, adjv);
    softmax_h<<<64, 256, 0, stream>>>(adjv, sh);
    softmax_o<<<256, 64, 0, stream>>>(adjv, so);

    // ---- o2s -> msg_h -> h_enc'
    run_gemm(stream, enc_bf, o2sW1t, a1o2s, o2s_b1, 256, 1024, 1024, 1024, false, false);
    run_gemm(stream, sp, o2sW2t, a2_tmp, o2s_b2, P_, 1024, 1024, 1024, false, true);
    hbuild<<<8192, 256, 0, stream>>>(a1o2s, nullptr, nullptr, a2_tmp, Hbuf, 1);
    run_gemm(stream, Hbuf, o2sW3t, Mbuf, nullptr, P_, 1024, 1024, 1024, false, false);
    msgh_k<<<dim3(64, 4), 256, 0, stream>>>(Mbuf, sh, sb3_o2s, msgh);
    ln_k<<<64, 256, 0, stream>>>(node_enc, msgh, lnh_g, lnh_b, henc_bf);

    // ---- s2o -> msg_o -> o_enc'
    run_gemm(stream, henc_bf, s2oW1t, a1s2o, s2o_b1, 64, 1024, 1024, 1024, false, false);
    run_gemm(stream, sp, s2oW2t, a2_tmp, s2o_b2, P_, 1024, 1024, 1024, false, true);
    hbuild<<<8192, 256, 0, stream>>>(a1s2o, nullptr, nullptr, a2_tmp, Hbuf, 2);
    run_gemm(stream, Hbuf, s2oW3t, Mbuf, nullptr, P_, 1024, 1024, 1024, false, false);
    msgo_k<<<dim3(256, 4), 256, 0, stream>>>(Mbuf, so, sb3_s2o, msgo);
    ln_k<<<256, 256, 0, stream>>>(node_enc, msgo, lno_g, lno_b, oenc_bf);

    // ---- f_local -> d_out[:, 0:1024]
    run_gemm(stream, henc_bf, ahW1tT, Ah, nullptr, 64,  1024, 1024, 1024, false, false);
    run_gemm(stream, oenc_bf, ahW1tB, Ao, nullptr, 256, 1024, 1024, 1024, false, false);
    hbuild<<<8192, 256, 0, stream>>>(Ah, Ao, ah_b1, a2_ah, Hbuf, 0);
    run_gemm(stream, Hbuf, ahW3t, (float*)d_out, sb3_ah, P_, 1024, 1024, 2048, true, false);

    // ---- f_glob -> d_out[:, 1024:2048]
    a1g_k<<<4, 256, 0, stream>>>(gfeat, ahg_W1, ahg_b1, a1g);
    run_gemm(stream, sp, ahgW2t, a2_tmp, ahg_b2, P_, 1024, 1024, 1024, false, true);
    hbuild<<<8192, 256, 0, stream>>>(a1g, nullptr, nullptr, a2_tmp, Hbuf, 3);
    run_gemm(stream, Hbuf, ahgW3t, (float*)d_out + 1024, sb3_ahg, P_, 1024, 1024, 2048, true, false);

    (void)in_sizes; (void)n_in; (void)out_size; (void)ws_size;
}

// Round 2
// 848.961 us; speedup vs baseline: 1.2070x; 1.2070x over previous
//
#include <hip/hip_runtime.h>
#include <hip/hip_bf16.h>
#include <stdint.h>
#include <stddef.h>

using bf16 = __hip_bfloat16;
typedef __bf16 bf16x8 __attribute__((ext_vector_type(8)));
typedef float f32x4 __attribute__((ext_vector_type(4)));

#define P_  16384

// ---------------------------------------------------------------- async g->LDS
__device__ __forceinline__ void gload16(const void* g, void* l) {
    __builtin_amdgcn_global_load_lds((const __attribute__((address_space(1))) void*)g,
                                     (__attribute__((address_space(3))) void*)l, 16, 0, 0);
}

// ---------------------------------------------------------------- GEMM (B^T)
// C[M,N] = A[M,K] @ B^T, B stored N x K row-major, both bf16.
// 128x128 tile, BK=32, 4 waves 2x2, 4x4 frags of 16x16x32 MFMA.
// MODE 0: store fp32 (+bias/relu)          MODE 1: store bf16 (+bias/relu)
// MODE 2: split-K, atomicAdd fp32 (grid.z = K/kchunk)
// MODE 3: H=relu((aux1[p&255,c]+aux2[c])*(acc+bias[c])) -> bf16 C[p,c]        (o2s)
// MODE 4: H=relu((aux1[p>>8,c]+aux2[c])*(acc+bias[c])) -> bf16 C[(p&255)*64+(p>>8),c] (s2o)
// MODE 5: H=relu(aux1[c]*(acc+bias[c])) -> bf16 C[p,c]                        (ahg)
// MODE 6: adj: atomicAdd(C[p], sum_c relu(acc+bias[c])*aux1[c])               (weights->adj)
// MODE 7: msum groups of 256 rows: atomicAdd(C[(p>>8)*1024+c], aux1[p]*acc)   (o2s msg_h)
// MODE 8: msum groups of 64 rows:  atomicAdd(C[(p>>6)*1024+c], aux1[p]*acc)   (s2o msg_o)
template<int MODE, bool RELU, bool BIAS>
__global__ __launch_bounds__(256, 3)
void gemm_bt(const bf16* __restrict__ A, const bf16* __restrict__ B,
             void* __restrict__ C, const float* __restrict__ bias,
             const float* __restrict__ aux1, const float* __restrict__ aux2,
             int M, int N, int K, int ldc, int kchunk)
{
    __shared__ __align__(16) bf16 As[128 * 32];
    __shared__ __align__(16) bf16 Bs[128 * 32];

    const int tid  = threadIdx.x;
    const int wave = tid >> 6;
    const int lane = tid & 63;
    const int tileM = blockIdx.x * 128;
    const int tileN = blockIdx.y * 128;
    const int wr = (wave >> 1) << 6;
    const int wc = (wave & 1) << 6;

    f32x4 acc[4][4] = {};

    int arow[2], brow[2], ako[2];
    #pragma unroll
    for (int j = 0; j < 2; ++j) {
        int c  = wave * 128 + j * 64 + lane;
        int r  = c >> 2;
        ako[j] = (c & 3) << 3;
        int gr = tileM + r; if (gr > M - 1) gr = M - 1;
        arow[j] = gr;
        int gn = tileN + r; if (gn > N - 1) gn = N - 1;
        brow[j] = gn;
    }
    const int m0   = wr + (lane & 15);
    const int n0   = wc + (lane & 15);
    const int koff = (lane >> 4) << 3;

    int kbeg = 0, kend = K;
    if constexpr (MODE == 2) { kbeg = blockIdx.z * kchunk; kend = kbeg + kchunk; }

    for (int k0 = kbeg; k0 < kend; k0 += 32) {
        #pragma unroll
        for (int j = 0; j < 2; ++j) {
            int c = wave * 128 + j * 64 + lane;
            gload16(A + (size_t)arow[j] * K + k0 + ako[j], (void*)(As + c * 8));
            gload16(B + (size_t)brow[j] * K + k0 + ako[j], (void*)(Bs + c * 8));
        }
        __syncthreads();
        bf16x8 af[4], bfv[4];
        #pragma unroll
        for (int i = 0; i < 4; ++i) {
            af[i]  = *(const bf16x8*)(As + (m0 + i * 16) * 32 + koff);
            bfv[i] = *(const bf16x8*)(Bs + (n0 + i * 16) * 32 + koff);
        }
        #pragma unroll
        for (int i = 0; i < 4; ++i)
            #pragma unroll
            for (int j = 0; j < 4; ++j)
                acc[i][j] = __builtin_amdgcn_mfma_f32_16x16x32_bf16(af[i], bfv[j], acc[i][j], 0, 0, 0);
        __syncthreads();
    }

    const int rbase = tileM + wr + ((lane >> 4) << 2);
    const int cbase = tileN + wc + (lane & 15);

    if constexpr (MODE == 0 || MODE == 1) {
        #pragma unroll
        for (int i = 0; i < 4; ++i)
            #pragma unroll
            for (int j = 0; j < 4; ++j)
                #pragma unroll
                for (int r = 0; r < 4; ++r) {
                    int grow = rbase + i * 16 + r;
                    if (grow >= M) continue;
                    int gcol = cbase + j * 16;
                    float v = acc[i][j][r];
                    if (BIAS) v += bias[gcol];
                    if (RELU) v = fmaxf(v, 0.f);
                    if (MODE == 1) ((bf16*)C)[(size_t)grow * ldc + gcol] = __float2bfloat16(v);
                    else           ((float*)C)[(size_t)grow * ldc + gcol] = v;
                }
    } else if constexpr (MODE == 2) {
        #pragma unroll
        for (int i = 0; i < 4; ++i)
            #pragma unroll
            for (int j = 0; j < 4; ++j)
                #pragma unroll
                for (int r = 0; r < 4; ++r) {
                    int grow = rbase + i * 16 + r;
                    if (grow >= M) continue;
                    atomicAdd((float*)C + (size_t)grow * ldc + cbase + j * 16, acc[i][j][r]);
                }
    } else if constexpr (MODE >= 3 && MODE <= 5) {
        #pragma unroll
        for (int i = 0; i < 4; ++i)
            #pragma unroll
            for (int j = 0; j < 4; ++j)
                #pragma unroll
                for (int r = 0; r < 4; ++r) {
                    int p    = rbase + i * 16 + r;
                    int gcol = cbase + j * 16;
                    float a2v = acc[i][j][r] + bias[gcol];
                    float a1v;
                    if (MODE == 3) a1v = aux1[((size_t)(p & 255) << 10) + gcol] + aux2[gcol];
                    if (MODE == 4) a1v = aux1[((size_t)(p >> 8)  << 10) + gcol] + aux2[gcol];
                    if (MODE == 5) a1v = aux1[gcol];
                    float h = fmaxf(a1v * a2v, 0.f);
                    size_t orow = (MODE == 4) ? (size_t)((p & 255) * 64 + (p >> 8)) : (size_t)p;
                    ((bf16*)C)[orow * 1024 + gcol] = __float2bfloat16(h);
                }
    } else if constexpr (MODE == 6) {
        #pragma unroll
        for (int i = 0; i < 4; ++i)
            #pragma unroll
            for (int r = 0; r < 4; ++r) {
                float s = 0.f;
                #pragma unroll
                for (int j = 0; j < 4; ++j) {
                    int gcol = cbase + j * 16;
                    s += fmaxf(acc[i][j][r] + bias[gcol], 0.f) * aux1[gcol];
                }
                s += __shfl_xor(s, 1); s += __shfl_xor(s, 2);
                s += __shfl_xor(s, 4); s += __shfl_xor(s, 8);
                if ((lane & 15) == 0)
                    atomicAdd((float*)C + rbase + i * 16 + r, s);
            }
    } else {  // MODE 7 / 8
        float s[4] = {0.f, 0.f, 0.f, 0.f};
        #pragma unroll
        for (int i = 0; i < 4; ++i)
            #pragma unroll
            for (int r = 0; r < 4; ++r) {
                float wv = aux1[rbase + i * 16 + r];
                #pragma unroll
                for (int j = 0; j < 4; ++j) s[j] += wv * acc[i][j][r];
            }
        #pragma unroll
        for (int j = 0; j < 4; ++j) {
            s[j] += __shfl_xor(s[j], 16);
            s[j] += __shfl_xor(s[j], 32);
        }
        if (lane < 16) {
            int outrow = (tileM + wr) >> (MODE == 7 ? 8 : 6);
            #pragma unroll
            for (int j = 0; j < 4; ++j)
                atomicAdd((float*)C + (size_t)outrow * 1024 + cbase + j * 16, s[j]);
        }
    }
}

// ---------------------------------------------------------------- converters
__global__ void transp(const float* __restrict__ src, bf16* __restrict__ dst,
                       int rows, int cols, size_t sstride, size_t dstride)
{
    const float* s = src + blockIdx.z * sstride;
    bf16*        d = dst + blockIdx.z * dstride;
    __shared__ float tile[32][33];
    int c0 = blockIdx.x * 32, r0 = blockIdx.y * 32;
    int x = threadIdx.x, y = threadIdx.y;   // (32, 8)
    for (int yy = y; yy < 32; yy += 8) {
        int r = r0 + yy, c = c0 + x;
        tile[yy][x] = (r < rows && c < cols) ? s[(size_t)r * cols + c] : 0.f;
    }
    __syncthreads();
    for (int yy = y; yy < 32; yy += 8) {
        int c = c0 + yy, r = r0 + x;
        if (c < cols && r < rows) d[(size_t)c * rows + r] = __float2bfloat16(tile[x][yy]);
    }
}

__global__ void conv_spw1(const float* __restrict__ src, bf16* __restrict__ dst) {
    int i = blockIdx.x * 256 + threadIdx.x;        // 128*64 (B^T padded K 36->64)
    if (i >= 128 * 64) return;
    int k = i & 63, n = i >> 6;
    dst[i] = __float2bfloat16(k < 36 ? src[k * 128 + n] : 0.f);
}

__global__ void pad_spatial(const float* __restrict__ src, bf16* __restrict__ dst) {
    int i = blockIdx.x * 256 + threadIdx.x;        // P*64
    int k = i & 63, p = i >> 6;
    dst[i] = __float2bfloat16(k < 36 ? src[p * 36 + k] : 0.f);
}

__global__ void cast_f2b(const float* __restrict__ src, bf16* __restrict__ dst, int n) {
    int i = blockIdx.x * 256 + threadIdx.x;
    if (i < n) dst[i] = __float2bfloat16(src[i]);
}

__global__ void sumb3_k(const float* __restrict__ b3, float* __restrict__ out) {
    int r = blockIdx.x * 256 + threadIdx.x;        // 1024
    float s = 0.f;
    #pragma unroll
    for (int c = 0; c < 16; ++c) s += b3[c * 1024 + r];
    out[r] = s;
}

// H = relu((Ah[p>>8] + Ao[p&255] + b1) * a2)   (ah head only)
__global__ void hbuild(const float* __restrict__ Ah, const float* __restrict__ Ao,
                       const float* __restrict__ b1, const bf16* __restrict__ a2,
                       bf16* __restrict__ H)
{
    size_t base = ((size_t)blockIdx.x * 256 + threadIdx.x) * 8;
    int cs = (int)(base & 1023);
    int p  = (int)(base >> 10);
    const float* ph = Ah + ((size_t)(p >> 8) << 10) + cs;
    const float* po = Ao + ((size_t)(p & 255) << 10) + cs;
    bf16x8 av = *(const bf16x8*)(a2 + base);
    bf16x8 o;
    #pragma unroll
    for (int j = 0; j < 8; ++j) {
        float a1 = ph[j] + po[j] + b1[cs + j];
        o[j] = (__bf16)fmaxf(a1 * (float)av[j], 0.f);
    }
    *(bf16x8*)(H + base) = o;
}

// ---------------------------------------------------------------- softmax / LN
__global__ void softmax_h(const float* __restrict__ adj, float* __restrict__ sh) {
    int h = blockIdx.x, n = threadIdx.x;           // 64 x 256
    __shared__ float red[256];
    float v = adj[h * 256 + n];
    red[n] = v; __syncthreads();
    for (int s = 128; s > 0; s >>= 1) { if (n < s) red[n] = fmaxf(red[n], red[n + s]); __syncthreads(); }
    float m = red[0]; __syncthreads();
    float e = expf(v - m);
    red[n] = e; __syncthreads();
    for (int s = 128; s > 0; s >>= 1) { if (n < s) red[n] += red[n + s]; __syncthreads(); }
    sh[h * 256 + n] = e / red[0];
}

__global__ void softmax_o(const float* __restrict__ adj, float* __restrict__ so) {
    int n = blockIdx.x, h = threadIdx.x;           // 256 x 64
    float v = adj[h * 256 + n];
    float m = v;
    #pragma unroll
    for (int off = 32; off; off >>= 1) m = fmaxf(m, __shfl_xor(m, off));
    float e = expf(v - m);
    float s = e;
    #pragma unroll
    for (int off = 32; off; off >>= 1) s += __shfl_xor(s, off);
    so[n * 64 + h] = e / s;
}

// out = LN(x + relu(msgraw + sb3)) * g + b, cast bf16
__global__ void ln_k(const float* __restrict__ x, const float* __restrict__ msgraw,
                     const float* __restrict__ sb3,
                     const float* __restrict__ g, const float* __restrict__ bb,
                     bf16* __restrict__ out)
{
    int row = blockIdx.x, t = threadIdx.x;         // rows x 256, E=1024
    const float* xr = x + (size_t)row * 1024;
    const float* mr = msgraw + (size_t)row * 1024;
    float v[4]; float s = 0.f, ss = 0.f;
    #pragma unroll
    for (int j = 0; j < 4; ++j) {
        int i = t + j * 256;
        v[j] = xr[i] + fmaxf(mr[i] + sb3[i], 0.f);
        s += v[j]; ss += v[j] * v[j];
    }
    __shared__ float r1[256], r2[256];
    r1[t] = s; r2[t] = ss; __syncthreads();
    for (int k = 128; k > 0; k >>= 1) { if (t < k) { r1[t] += r1[t + k]; r2[t] += r2[t + k]; } __syncthreads(); }
    float mean = r1[0] * (1.f / 1024.f);
    float var  = r2[0] * (1.f / 1024.f) - mean * mean;
    float inv  = rsqrtf(var + 1e-5f);
    #pragma unroll
    for (int j = 0; j < 4; ++j) {
        int i = t + j * 256;
        out[(size_t)row * 1024 + i] = __float2bfloat16((v[j] - mean) * inv * g[i] + bb[i]);
    }
}

__global__ void a1g_k(const float* __restrict__ gf, const float* __restrict__ W1,
                      const float* __restrict__ b1, float* __restrict__ a1g)
{
    int cs = blockIdx.x * 256 + threadIdx.x;       // 1024
    int c = cs >> 6, s = cs & 63;
    float acc = b1[cs];
    for (int g = 0; g < 256; ++g) acc += gf[g] * W1[((size_t)c * 256 + g) * 64 + s];
    a1g[cs] = acc;
}

// ---------------------------------------------------------------- launch
extern "C" void kernel_launch(void* const* d_in, const int* in_sizes, int n_in,
                              void* d_out, int out_size, void* d_ws, size_t ws_size,
                              hipStream_t stream)
{
    const float* node_enc = (const float*)d_in[0];
    const float* spatial  = (const float*)d_in[1];
    const float* gfeat    = (const float*)d_in[2];
    const float* sp_W1 = (const float*)d_in[3];  const float* sp_b1 = (const float*)d_in[4];
    const float* sp_W2 = (const float*)d_in[5];  const float* sp_b2 = (const float*)d_in[6];
    const float* sp_W3 = (const float*)d_in[7];  const float* sp_b3 = (const float*)d_in[8];
    const float* ah_W1 = (const float*)d_in[9];  const float* ah_b1 = (const float*)d_in[10];
    const float* ah_W2 = (const float*)d_in[11]; const float* ah_b2 = (const float*)d_in[12];
    const float* ah_W3 = (const float*)d_in[13]; const float* ah_b3 = (const float*)d_in[14];
    const float* o2s_W1 = (const float*)d_in[15]; const float* o2s_b1 = (const float*)d_in[16];
    const float* o2s_W2 = (const float*)d_in[17]; const float* o2s_b2 = (const float*)d_in[18];
    const float* o2s_W3 = (const float*)d_in[19]; const float* o2s_b3 = (const float*)d_in[20];
    const float* s2o_W1 = (const float*)d_in[21]; const float* s2o_b1 = (const float*)d_in[22];
    const float* s2o_W2 = (const float*)d_in[23]; const float* s2o_b2 = (const float*)d_in[24];
    const float* s2o_W3 = (const float*)d_in[25]; const float* s2o_b3 = (const float*)d_in[26];
    const float* ahg_W1 = (const float*)d_in[27]; const float* ahg_b1 = (const float*)d_in[28];
    const float* ahg_W2 = (const float*)d_in[29]; const float* ahg_b2 = (const float*)d_in[30];
    const float* ahg_W3 = (const float*)d_in[31]; const float* ahg_b3 = (const float*)d_in[32];
    const float* adj_W = (const float*)d_in[33];
    const float* lnh_g = (const float*)d_in[35]; const float* lnh_b = (const float*)d_in[36];
    const float* lno_g = (const float*)d_in[37]; const float* lno_b = (const float*)d_in[38];

    char* w = (char*)d_ws;
    auto alloc = [&](size_t bytes) { char* p = w; w += (bytes + 255) & ~(size_t)255; return p; };
    bf16*  sp      = (bf16*)alloc((size_t)P_ * 1024 * 2);
    bf16*  a2_ah   = (bf16*)alloc((size_t)P_ * 1024 * 2);
    bf16*  Hbuf    = (bf16*)alloc((size_t)P_ * 1024 * 2);
    bf16*  spat_pad= (bf16*)alloc((size_t)P_ * 64 * 2);
    bf16*  spL1    = (bf16*)alloc((size_t)P_ * 128 * 2);
    bf16*  spL2    = (bf16*)alloc((size_t)P_ * 256 * 2);
    bf16*  enc_bf  = (bf16*)alloc(256 * 1024 * 2);
    bf16*  henc_bf = (bf16*)alloc(64 * 1024 * 2);
    bf16*  oenc_bf = (bf16*)alloc(256 * 1024 * 2);
    bf16*  spW1t   = (bf16*)alloc(128 * 64 * 2);
    bf16*  spW2t   = (bf16*)alloc(256 * 128 * 2);
    bf16*  spW3t   = (bf16*)alloc(1024 * 256 * 2);
    bf16*  ahW1tT  = (bf16*)alloc(1024 * 1024 * 2);
    bf16*  ahW1tB  = (bf16*)alloc(1024 * 1024 * 2);
    bf16*  ahW2t   = (bf16*)alloc(1024 * 1024 * 2);
    bf16*  ahW3t   = (bf16*)alloc(1024 * 1024 * 2);
    bf16*  o2sW1t  = (bf16*)alloc(1024 * 1024 * 2);
    bf16*  o2sW2t  = (bf16*)alloc(1024 * 1024 * 2);
    bf16*  o2sW3t  = (bf16*)alloc(1024 * 1024 * 2);
    bf16*  s2oW1t  = (bf16*)alloc(1024 * 1024 * 2);
    bf16*  s2oW2t  = (bf16*)alloc(1024 * 1024 * 2);
    bf16*  s2oW3t  = (bf16*)alloc(1024 * 1024 * 2);
    bf16*  ahgW2t  = (bf16*)alloc(1024 * 1024 * 2);
    bf16*  ahgW3t  = (bf16*)alloc(1024 * 1024 * 2);
    float* Ah    = (float*)alloc(64 * 1024 * 4);     // \ contiguous zero-init
    float* Ao    = (float*)alloc(256 * 1024 * 4);    // |
    float* a1o2s = (float*)alloc(256 * 1024 * 4);    // |
    float* a1s2o = (float*)alloc(64 * 1024 * 4);     // /
    float* a1g   = (float*)alloc(1024 * 4);
    float* adjv  = (float*)alloc(P_ * 4);            // \ contiguous zero-init
    float* sh    = (float*)alloc(P_ * 4);
    float* so    = (float*)alloc(P_ * 4);
    float* msgh  = (float*)alloc(64 * 1024 * 4);
    float* msgo  = (float*)alloc(256 * 1024 * 4);
    float* sb3_ah  = (float*)alloc(4096);
    float* sb3_o2s = (float*)alloc(4096);
    float* sb3_s2o = (float*)alloc(4096);
    float* sb3_ahg = (float*)alloc(4096);

    // zero-init accumulation targets (graph-capturable memset nodes)
    hipMemsetAsync(Ah,   0, (64 + 256 + 256 + 64) * 1024 * 4, stream);
    hipMemsetAsync(adjv, 0, P_ * 4, stream);
    hipMemsetAsync(msgh, 0, 64 * 1024 * 4, stream);
    hipMemsetAsync(msgo, 0, 256 * 1024 * 4, stream);

    dim3 tb(32, 8);
    conv_spw1<<<32, 256, 0, stream>>>(sp_W1, spW1t);
    transp<<<dim3(8, 4, 1),  tb, 0, stream>>>(sp_W2, spW2t, 128, 256, 0, 0);
    transp<<<dim3(32, 8, 1), tb, 0, stream>>>(sp_W3, spW3t, 256, 1024, 0, 0);
    transp<<<dim3(2, 32, 16), tb, 0, stream>>>(ah_W1,                     ahW1tT, 1024, 64, (size_t)2048 * 64, (size_t)64 * 1024);
    transp<<<dim3(2, 32, 16), tb, 0, stream>>>(ah_W1 + (size_t)1024 * 64, ahW1tB, 1024, 64, (size_t)2048 * 64, (size_t)64 * 1024);
    transp<<<dim3(2, 32, 16), tb, 0, stream>>>(ah_W2,  ahW2t,  1024, 64, 65536, 65536);
    transp<<<dim3(2, 32, 16), tb, 0, stream>>>(o2s_W1, o2sW1t, 1024, 64, 65536, 65536);
    transp<<<dim3(2, 32, 16), tb, 0, stream>>>(o2s_W2, o2sW2t, 1024, 64, 65536, 65536);
    transp<<<dim3(2, 32, 16), tb, 0, stream>>>(s2o_W1, s2oW1t, 1024, 64, 65536, 65536);
    transp<<<dim3(2, 32, 16), tb, 0, stream>>>(s2o_W2, s2oW2t, 1024, 64, 65536, 65536);
    transp<<<dim3(2, 32, 16), tb, 0, stream>>>(ahg_W2, ahgW2t, 1024, 64, 65536, 65536);
    transp<<<dim3(32, 32, 1), tb, 0, stream>>>(ah_W3,  ahW3t,  1024, 1024, 0, 0);
    transp<<<dim3(32, 32, 1), tb, 0, stream>>>(o2s_W3, o2sW3t, 1024, 1024, 0, 0);
    transp<<<dim3(32, 32, 1), tb, 0, stream>>>(s2o_W3, s2oW3t, 1024, 1024, 0, 0);
    transp<<<dim3(32, 32, 1), tb, 0, stream>>>(ahg_W3, ahgW3t, 1024, 1024, 0, 0);
    pad_spatial<<<4096, 256, 0, stream>>>(spatial, spat_pad);
    cast_f2b<<<1024, 256, 0, stream>>>(node_enc, enc_bf, 256 * 1024);
    sumb3_k<<<4, 256, 0, stream>>>(ah_b3,  sb3_ah);
    sumb3_k<<<4, 256, 0, stream>>>(o2s_b3, sb3_o2s);
    sumb3_k<<<4, 256, 0, stream>>>(s2o_b3, sb3_s2o);
    sumb3_k<<<4, 256, 0, stream>>>(ahg_b3, sb3_ahg);
    a1g_k<<<4, 256, 0, stream>>>(gfeat, ahg_W1, ahg_b1, a1g);

    #define G128(M, N) dim3(((M) + 127) / 128, (N) / 128), dim3(256)
    #define GSPL(M)    dim3(((M) + 127) / 128, 8, 8), dim3(256)

    // ---- sp MLP
    gemm_bt<1, true, true><<<G128(P_, 128),  0, stream>>>(spat_pad, spW1t, spL1, sp_b1, nullptr, nullptr, P_, 128, 64, 128, 0);
    gemm_bt<1, true, true><<<G128(P_, 256),  0, stream>>>(spL1,     spW2t, spL2, sp_b2, nullptr, nullptr, P_, 256, 128, 256, 0);
    gemm_bt<1, true, true><<<G128(P_, 1024), 0, stream>>>(spL2,     spW3t, sp,   sp_b3, nullptr, nullptr, P_, 1024, 256, 1024, 0);

    // ---- a2_ah (shared by weights & f_local)
    gemm_bt<1, false, true><<<G128(P_, 1024), 0, stream>>>(sp, ahW2t, a2_ah, ah_b2, nullptr, nullptr, P_, 1024, 1024, 1024, 0);

    // ---- weights -> adj (fused reduction) -> softmaxes
    gemm_bt<2, false, false><<<GSPL(64),  0, stream>>>(enc_bf, ahW1tT, Ah, nullptr, nullptr, nullptr, 64,  1024, 1024, 1024, 128);
    gemm_bt<2, false, false><<<GSPL(256), 0, stream>>>(enc_bf, ahW1tB, Ao, nullptr, nullptr, nullptr, 256, 1024, 1024, 1024, 128);
    hbuild<<<8192, 256, 0, stream>>>(Ah, Ao, ah_b1, a2_ah, Hbuf);
    gemm_bt<6, false, false><<<G128(P_, 1024), 0, stream>>>(Hbuf, ahW3t, adjv, sb3_ah, adj_W, nullptr, P_, 1024, 1024, 1024, 0);
    softmax_h<<<64, 256, 0, stream>>>(adjv, sh);
    softmax_o<<<256, 64, 0, stream>>>(adjv, so);

    // ---- o2s -> msg_h -> h_enc'
    gemm_bt<2, false, false><<<GSPL(256), 0, stream>>>(enc_bf, o2sW1t, a1o2s, nullptr, nullptr, nullptr, 256, 1024, 1024, 1024, 128);
    gemm_bt<3, false, false><<<G128(P_, 1024), 0, stream>>>(sp, o2sW2t, Hbuf, o2s_b2, a1o2s, o2s_b1, P_, 1024, 1024, 1024, 0);
    gemm_bt<7, false, false><<<G128(P_, 1024), 0, stream>>>(Hbuf, o2sW3t, msgh, nullptr, sh, nullptr, P_, 1024, 1024, 1024, 0);
    ln_k<<<64, 256, 0, stream>>>(node_enc, msgh, sb3_o2s, lnh_g, lnh_b, henc_bf);

    // ---- s2o -> msg_o -> o_enc'  (H written in p' = n*64+h order)
    gemm_bt<2, false, false><<<GSPL(64), 0, stream>>>(henc_bf, s2oW1t, a1s2o, nullptr, nullptr, nullptr, 64, 1024, 1024, 1024, 128);
    gemm_bt<4, false, false><<<G128(P_, 1024), 0, stream>>>(sp, s2oW2t, Hbuf, s2o_b2, a1s2o, s2o_b1, P_, 1024, 1024, 1024, 0);
    gemm_bt<8, false, false><<<G128(P_, 1024), 0, stream>>>(Hbuf, s2oW3t, msgo, nullptr, so, nullptr, P_, 1024, 1024, 1024, 0);
    ln_k<<<256, 256, 0, stream>>>(node_enc, msgo, sb3_s2o, lno_g, lno_b, oenc_bf);

    // ---- f_local -> d_out[:, 0:1024]
    hipMemsetAsync(Ah, 0, (64 + 256) * 1024 * 4, stream);
    gemm_bt<2, false, false><<<GSPL(64),  0, stream>>>(henc_bf, ahW1tT, Ah, nullptr, nullptr, nullptr, 64,  1024, 1024, 1024, 128);
    gemm_bt<2, false, false><<<GSPL(256), 0, stream>>>(oenc_bf, ahW1tB, Ao, nullptr, nullptr, nullptr, 256, 1024, 1024, 1024, 128);
    hbuild<<<8192, 256, 0, stream>>>(Ah, Ao, ah_b1, a2_ah, Hbuf);
    gemm_bt<0, true, true><<<G128(P_, 1024), 0, stream>>>(Hbuf, ahW3t, (float*)d_out, sb3_ah, nullptr, nullptr, P_, 1024, 1024, 2048, 0);

    // ---- f_glob -> d_out[:, 1024:2048]
    gemm_bt<5, false, false><<<G128(P_, 1024), 0, stream>>>(sp, ahgW2t, Hbuf, ahg_b2, a1g, nullptr, P_, 1024, 1024, 1024, 0);
    gemm_bt<0, true, true><<<G128(P_, 1024), 0, stream>>>(Hbuf, ahgW3t, (float*)d_out + 1024, sb3_ahg, nullptr, nullptr, P_, 1024, 1024, 2048, 0);

    (void)in_sizes; (void)n_in; (void)out_size; (void)ws_size;
}

// Round 3
// 809.771 us; speedup vs baseline: 1.2654x; 1.0484x over previous
//
#include <hip/hip_runtime.h>
#include <hip/hip_bf16.h>
#include <stdint.h>
#include <stddef.h>

using bf16 = __hip_bfloat16;
typedef __bf16 bf16x8 __attribute__((ext_vector_type(8)));
typedef float f32x4 __attribute__((ext_vector_type(4)));

#define P_  16384

// ---------------------------------------------------------------- async g->LDS
__device__ __forceinline__ void gload16(const void* g, void* l) {
    __builtin_amdgcn_global_load_lds((const __attribute__((address_space(1))) void*)g,
                                     (__attribute__((address_space(3))) void*)l, 16, 0, 0);
}

// ---------------------------------------------------------------- GEMM (B^T)
struct GArgs {
    const bf16* A; const bf16* B; void* C;
    const float* bias;    // column bias
    const float* aux1;    // per-row weight (M7/8), adj_W (M6), a1 source (M4/M9)
    const float* aux2;    // b1 for fused H (M4)
    int M, N, K, ldc, kchunk, aux_ld;
    // MODE 9 extras:
    void* C2; void* C3;                     // H_o2s, H_ahg
    const float* b2a; const float* b2b; const float* b2c;  // ah_b2, o2s_b2, ahg_b2
    const float* b1o;  const float* a1gv;                  // o2s_b1, a1g
};

// C[M,N] = A[M,K] @ B^T, B stored N x K row-major, both bf16.
// 128x128 tile, BK=32, 4 waves 2x2, 4x4 frags of 16x16x32 MFMA.
// MODE 0: store fp32 (+bias/relu)       MODE 1: store bf16 (+bias/relu)
// MODE 2: split-K, atomicAdd fp32 (grid.z = K/kchunk)
// MODE 4: H=relu((aux1[p>>8,c]+aux2[c])*(acc+bias[c])) -> bf16 C[(p&255)*64+(p>>8),c]
// MODE 6: adj: atomicAdd(C[p], sum_c relu(acc+bias[c])*aux1[c])
// MODE 7: group-256 rows: atomicAdd(C[(p>>8)*1024+c], aux1[p]*acc)
// MODE 8: group-64 rows:  atomicAdd(C[(p>>6)*1024+c], aux1[p]*acc)
// MODE 9: merged W2 trio: col-group 0 -> a2_ah bf16 (+b2a); group 1 -> H_o2s fused;
//         group 2 -> H_ahg fused
template<int MODE, bool RELU, bool BIAS>
__global__ __launch_bounds__(256, 3)
void gemm_bt(GArgs g)
{
    __shared__ __align__(16) bf16 As[128 * 32];
    __shared__ __align__(16) bf16 Bs[128 * 32];

    const int tid  = threadIdx.x;
    const int wave = tid >> 6;
    const int lane = tid & 63;
    const int tileM = blockIdx.x * 128;
    const int tileN = blockIdx.y * 128;
    const int wr = (wave >> 1) << 6;
    const int wc = (wave & 1) << 6;
    const int M = g.M, N = g.N, K = g.K;

    f32x4 acc[4][4] = {};

    int arow[2], brow[2], ako[2];
    #pragma unroll
    for (int j = 0; j < 2; ++j) {
        int c  = wave * 128 + j * 64 + lane;
        int r  = c >> 2;
        ako[j] = (c & 3) << 3;
        int gr = tileM + r; if (gr > M - 1) gr = M - 1;
        arow[j] = gr;
        int gn = tileN + r; if (gn > N - 1) gn = N - 1;
        brow[j] = gn;
    }
    const int m0   = wr + (lane & 15);
    const int n0   = wc + (lane & 15);
    const int koff = (lane >> 4) << 3;

    int kbeg = 0, kend = K;
    if constexpr (MODE == 2) { kbeg = blockIdx.z * g.kchunk; kend = kbeg + g.kchunk; }

    for (int k0 = kbeg; k0 < kend; k0 += 32) {
        #pragma unroll
        for (int j = 0; j < 2; ++j) {
            int c = wave * 128 + j * 64 + lane;
            gload16(g.A + (size_t)arow[j] * K + k0 + ako[j], (void*)(As + c * 8));
            gload16(g.B + (size_t)brow[j] * K + k0 + ako[j], (void*)(Bs + c * 8));
        }
        __syncthreads();
        bf16x8 af[4], bfv[4];
        #pragma unroll
        for (int i = 0; i < 4; ++i) {
            af[i]  = *(const bf16x8*)(As + (m0 + i * 16) * 32 + koff);
            bfv[i] = *(const bf16x8*)(Bs + (n0 + i * 16) * 32 + koff);
        }
        #pragma unroll
        for (int i = 0; i < 4; ++i)
            #pragma unroll
            for (int j = 0; j < 4; ++j)
                acc[i][j] = __builtin_amdgcn_mfma_f32_16x16x32_bf16(af[i], bfv[j], acc[i][j], 0, 0, 0);
        __syncthreads();
    }

    const int rbase = tileM + wr + ((lane >> 4) << 2);
    const int cbase = tileN + wc + (lane & 15);

    if constexpr (MODE == 0 || MODE == 1) {
        #pragma unroll
        for (int i = 0; i < 4; ++i)
            #pragma unroll
            for (int j = 0; j < 4; ++j)
                #pragma unroll
                for (int r = 0; r < 4; ++r) {
                    int grow = rbase + i * 16 + r;
                    if (grow >= M) continue;
                    int gcol = cbase + j * 16;
                    float v = acc[i][j][r];
                    if (BIAS) v += g.bias[gcol];
                    if (RELU) v = fmaxf(v, 0.f);
                    if (MODE == 1) ((bf16*)g.C)[(size_t)grow * g.ldc + gcol] = __float2bfloat16(v);
                    else           ((float*)g.C)[(size_t)grow * g.ldc + gcol] = v;
                }
    } else if constexpr (MODE == 2) {
        #pragma unroll
        for (int i = 0; i < 4; ++i)
            #pragma unroll
            for (int j = 0; j < 4; ++j)
                #pragma unroll
                for (int r = 0; r < 4; ++r) {
                    int grow = rbase + i * 16 + r;
                    if (grow >= M) continue;
                    atomicAdd((float*)g.C + (size_t)grow * g.ldc + cbase + j * 16, acc[i][j][r]);
                }
    } else if constexpr (MODE == 4) {
        #pragma unroll
        for (int i = 0; i < 4; ++i)
            #pragma unroll
            for (int j = 0; j < 4; ++j)
                #pragma unroll
                for (int r = 0; r < 4; ++r) {
                    int p    = rbase + i * 16 + r;
                    int gcol = cbase + j * 16;
                    float a2v = acc[i][j][r] + g.bias[gcol];
                    float a1v = g.aux1[(size_t)(p >> 8) * g.aux_ld + gcol] + g.aux2[gcol];
                    float h = fmaxf(a1v * a2v, 0.f);
                    size_t orow = (size_t)((p & 255) * 64 + (p >> 8));
                    ((bf16*)g.C)[orow * 1024 + gcol] = __float2bfloat16(h);
                }
    } else if constexpr (MODE == 6) {
        #pragma unroll
        for (int i = 0; i < 4; ++i)
            #pragma unroll
            for (int r = 0; r < 4; ++r) {
                float s = 0.f;
                #pragma unroll
                for (int j = 0; j < 4; ++j) {
                    int gcol = cbase + j * 16;
                    s += fmaxf(acc[i][j][r] + g.bias[gcol], 0.f) * g.aux1[gcol];
                }
                s += __shfl_xor(s, 1); s += __shfl_xor(s, 2);
                s += __shfl_xor(s, 4); s += __shfl_xor(s, 8);
                if ((lane & 15) == 0)
                    atomicAdd((float*)g.C + rbase + i * 16 + r, s);
            }
    } else if constexpr (MODE == 7 || MODE == 8) {
        float s[4] = {0.f, 0.f, 0.f, 0.f};
        #pragma unroll
        for (int i = 0; i < 4; ++i)
            #pragma unroll
            for (int r = 0; r < 4; ++r) {
                float wv = g.aux1[rbase + i * 16 + r];
                #pragma unroll
                for (int j = 0; j < 4; ++j) s[j] += wv * acc[i][j][r];
            }
        #pragma unroll
        for (int j = 0; j < 4; ++j) {
            s[j] += __shfl_xor(s[j], 16);
            s[j] += __shfl_xor(s[j], 32);
        }
        if (lane < 16) {
            int outrow = (tileM + wr) >> (MODE == 7 ? 8 : 6);
            #pragma unroll
            for (int j = 0; j < 4; ++j)
                atomicAdd((float*)g.C + (size_t)outrow * 1024 + cbase + j * 16, s[j]);
        }
    } else if constexpr (MODE == 9) {
        int grp = tileN >> 10;
        int lcb = (tileN & 1023) + wc + (lane & 15);
        #pragma unroll
        for (int i = 0; i < 4; ++i)
            #pragma unroll
            for (int j = 0; j < 4; ++j)
                #pragma unroll
                for (int r = 0; r < 4; ++r) {
                    int p    = rbase + i * 16 + r;
                    int lcol = lcb + j * 16;
                    float accv = acc[i][j][r];
                    if (grp == 0) {
                        ((bf16*)g.C)[(size_t)p * 1024 + lcol] =
                            __float2bfloat16(accv + g.b2a[lcol]);
                    } else if (grp == 1) {
                        float a2v = accv + g.b2b[lcol];
                        float a1v = g.aux1[(size_t)(p & 255) * g.aux_ld + lcol] + g.b1o[lcol];
                        ((bf16*)g.C2)[(size_t)p * 1024 + lcol] =
                            __float2bfloat16(fmaxf(a1v * a2v, 0.f));
                    } else {
                        float a2v = accv + g.b2c[lcol];
                        ((bf16*)g.C3)[(size_t)p * 1024 + lcol] =
                            __float2bfloat16(fmaxf(g.a1gv[lcol] * a2v, 0.f));
                    }
                }
    }
}

static GArgs mkargs(const bf16* A, const bf16* B, void* C, const float* bias,
                    const float* aux1, const float* aux2,
                    int M, int N, int K, int ldc, int kchunk, int aux_ld)
{
    GArgs g{};
    g.A = A; g.B = B; g.C = C; g.bias = bias; g.aux1 = aux1; g.aux2 = aux2;
    g.M = M; g.N = N; g.K = K; g.ldc = ldc; g.kchunk = kchunk; g.aux_ld = aux_ld;
    return g;
}

// ---------------------------------------------------------------- transposes
__global__ void transp(const float* __restrict__ src, bf16* __restrict__ dst,
                       int rows, int cols, size_t sstride, size_t dstride)
{
    const float* s = src + blockIdx.z * sstride;
    bf16*        d = dst + blockIdx.z * dstride;
    __shared__ float tile[32][33];
    int c0 = blockIdx.x * 32, r0 = blockIdx.y * 32;
    int x = threadIdx.x, y = threadIdx.y;   // (32, 8)
    for (int yy = y; yy < 32; yy += 8) {
        int r = r0 + yy, c = c0 + x;
        tile[yy][x] = (r < rows && c < cols) ? s[(size_t)r * cols + c] : 0.f;
    }
    __syncthreads();
    for (int yy = y; yy < 32; yy += 8) {
        int c = c0 + yy, r = r0 + x;
        if (c < cols && r < rows) d[(size_t)c * rows + r] = __float2bfloat16(tile[x][yy]);
    }
}

struct T8 { const float* s[8]; bf16* d[8]; size_t ss[8]; };
// 8 weights, each 16 z-slices of 1024x64 -> 64x1024; grid (2, 32, 128)
__global__ void transp64b(T8 t)
{
    int pair = blockIdx.z >> 4, slice = blockIdx.z & 15;
    const float* s = t.s[pair] + slice * t.ss[pair];
    bf16*        d = t.d[pair] + slice * 65536;
    __shared__ float tile[32][33];
    int c0 = blockIdx.x * 32, r0 = blockIdx.y * 32;
    int x = threadIdx.x, y = threadIdx.y;
    for (int yy = y; yy < 32; yy += 8)
        tile[yy][x] = s[(size_t)(r0 + yy) * 64 + c0 + x];
    __syncthreads();
    for (int yy = y; yy < 32; yy += 8)
        d[(size_t)(c0 + yy) * 1024 + r0 + x] = __float2bfloat16(tile[x][yy]);
}

struct T4 { const float* s[4]; bf16* d[4]; };
// 4 weights 1024x1024; grid (32, 32, 4)
__global__ void transp1024b(T4 t)
{
    const float* s = t.s[blockIdx.z];
    bf16*        d = t.d[blockIdx.z];
    __shared__ float tile[32][33];
    int c0 = blockIdx.x * 32, r0 = blockIdx.y * 32;
    int x = threadIdx.x, y = threadIdx.y;
    for (int yy = y; yy < 32; yy += 8)
        tile[yy][x] = s[(size_t)(r0 + yy) * 1024 + c0 + x];
    __syncthreads();
    for (int yy = y; yy < 32; yy += 8)
        d[(size_t)(c0 + yy) * 1024 + r0 + x] = __float2bfloat16(tile[x][yy]);
}

__global__ void conv_spw1(const float* __restrict__ src, bf16* __restrict__ dst) {
    int i = blockIdx.x * 256 + threadIdx.x;        // 128*64 (B^T padded K 36->64)
    if (i >= 128 * 64) return;
    int k = i & 63, n = i >> 6;
    dst[i] = __float2bfloat16(k < 36 ? src[k * 128 + n] : 0.f);
}

__global__ void pad_spatial(const float* __restrict__ src, bf16* __restrict__ dst) {
    int i = blockIdx.x * 256 + threadIdx.x;        // P*64
    int k = i & 63, p = i >> 6;
    dst[i] = __float2bfloat16(k < 36 ? src[p * 36 + k] : 0.f);
}

__global__ void cast_f2b(const float* __restrict__ src, bf16* __restrict__ dst, int n) {
    int i = blockIdx.x * 256 + threadIdx.x;
    if (i < n) dst[i] = __float2bfloat16(src[i]);
}

struct S4 { const float* s[4]; float* d[4]; };
__global__ void sumb3b(S4 a) {                      // grid 16 x 256
    int i = blockIdx.x * 256 + threadIdx.x;
    int pair = i >> 10, r = i & 1023;
    const float* b3 = a.s[pair];
    float s = 0.f;
    #pragma unroll
    for (int c = 0; c < 16; ++c) s += b3[c * 1024 + r];
    a.d[pair][r] = s;
}

// H = relu((Ah[p>>8] + Ao[p&255] + b1) * a2)
__global__ void hbuild(const float* __restrict__ Ah, int ah_ld,
                       const float* __restrict__ Ao, int ao_ld,
                       const float* __restrict__ b1, const bf16* __restrict__ a2,
                       bf16* __restrict__ H)
{
    size_t base = ((size_t)blockIdx.x * 256 + threadIdx.x) * 8;
    int cs = (int)(base & 1023);
    int p  = (int)(base >> 10);
    const float* ph = Ah + (size_t)(p >> 8) * ah_ld + cs;
    const float* po = Ao + (size_t)(p & 255) * ao_ld + cs;
    bf16x8 av = *(const bf16x8*)(a2 + base);
    bf16x8 o;
    #pragma unroll
    for (int j = 0; j < 8; ++j) {
        float a1 = ph[j] + po[j] + b1[cs + j];
        o[j] = (__bf16)fmaxf(a1 * (float)av[j], 0.f);
    }
    *(bf16x8*)(H + base) = o;
}

// ---------------------------------------------------------------- softmax / LN
__global__ void softmax_h(const float* __restrict__ adj, float* __restrict__ sh) {
    int h = blockIdx.x, n = threadIdx.x;
    __shared__ float red[256];
    float v = adj[h * 256 + n];
    red[n] = v; __syncthreads();
    for (int s = 128; s > 0; s >>= 1) { if (n < s) red[n] = fmaxf(red[n], red[n + s]); __syncthreads(); }
    float m = red[0]; __syncthreads();
    float e = expf(v - m);
    red[n] = e; __syncthreads();
    for (int s = 128; s > 0; s >>= 1) { if (n < s) red[n] += red[n + s]; __syncthreads(); }
    sh[h * 256 + n] = e / red[0];
}

__global__ void softmax_o(const float* __restrict__ adj, float* __restrict__ so) {
    int n = blockIdx.x, h = threadIdx.x;
    float v = adj[h * 256 + n];
    float m = v;
    #pragma unroll
    for (int off = 32; off; off >>= 1) m = fmaxf(m, __shfl_xor(m, off));
    float e = expf(v - m);
    float s = e;
    #pragma unroll
    for (int off = 32; off; off >>= 1) s += __shfl_xor(s, off);
    so[n * 64 + h] = e / s;
}

__global__ void ln_k(const float* __restrict__ x, const float* __restrict__ msgraw,
                     const float* __restrict__ sb3,
                     const float* __restrict__ g, const float* __restrict__ bb,
                     bf16* __restrict__ out)
{
    int row = blockIdx.x, t = threadIdx.x;
    const float* xr = x + (size_t)row * 1024;
    const float* mr = msgraw + (size_t)row * 1024;
    float v[4]; float s = 0.f, ss = 0.f;
    #pragma unroll
    for (int j = 0; j < 4; ++j) {
        int i = t + j * 256;
        v[j] = xr[i] + fmaxf(mr[i] + sb3[i], 0.f);
        s += v[j]; ss += v[j] * v[j];
    }
    __shared__ float r1[256], r2[256];
    r1[t] = s; r2[t] = ss; __syncthreads();
    for (int k = 128; k > 0; k >>= 1) { if (t < k) { r1[t] += r1[t + k]; r2[t] += r2[t + k]; } __syncthreads(); }
    float mean = r1[0] * (1.f / 1024.f);
    float var  = r2[0] * (1.f / 1024.f) - mean * mean;
    float inv  = rsqrtf(var + 1e-5f);
    #pragma unroll
    for (int j = 0; j < 4; ++j) {
        int i = t + j * 256;
        out[(size_t)row * 1024 + i] = __float2bfloat16((v[j] - mean) * inv * g[i] + bb[i]);
    }
}

__global__ void a1g_k(const float* __restrict__ gf, const float* __restrict__ W1,
                      const float* __restrict__ b1, float* __restrict__ a1g)
{
    int cs = blockIdx.x * 256 + threadIdx.x;
    int c = cs >> 6, s = cs & 63;
    float acc = b1[cs];
    for (int g = 0; g < 256; ++g) acc += gf[g] * W1[((size_t)c * 256 + g) * 64 + s];
    a1g[cs] = acc;
}

// ---------------------------------------------------------------- launch
extern "C" void kernel_launch(void* const* d_in, const int* in_sizes, int n_in,
                              void* d_out, int out_size, void* d_ws, size_t ws_size,
                              hipStream_t stream)
{
    const float* node_enc = (const float*)d_in[0];
    const float* spatial  = (const float*)d_in[1];
    const float* gfeat    = (const float*)d_in[2];
    const float* sp_W1 = (const float*)d_in[3];  const float* sp_b1 = (const float*)d_in[4];
    const float* sp_W2 = (const float*)d_in[5];  const float* sp_b2 = (const float*)d_in[6];
    const float* sp_W3 = (const float*)d_in[7];  const float* sp_b3 = (const float*)d_in[8];
    const float* ah_W1 = (const float*)d_in[9];  const float* ah_b1 = (const float*)d_in[10];
    const float* ah_W2 = (const float*)d_in[11]; const float* ah_b2 = (const float*)d_in[12];
    const float* ah_W3 = (const float*)d_in[13]; const float* ah_b3 = (const float*)d_in[14];
    const float* o2s_W1 = (const float*)d_in[15]; const float* o2s_b1 = (const float*)d_in[16];
    const float* o2s_W2 = (const float*)d_in[17]; const float* o2s_b2 = (const float*)d_in[18];
    const float* o2s_W3 = (const float*)d_in[19]; const float* o2s_b3 = (const float*)d_in[20];
    const float* s2o_W1 = (const float*)d_in[21]; const float* s2o_b1 = (const float*)d_in[22];
    const float* s2o_W2 = (const float*)d_in[23]; const float* s2o_b2 = (const float*)d_in[24];
    const float* s2o_W3 = (const float*)d_in[25]; const float* s2o_b3 = (const float*)d_in[26];
    const float* ahg_W1 = (const float*)d_in[27]; const float* ahg_b1 = (const float*)d_in[28];
    const float* ahg_W2 = (const float*)d_in[29]; const float* ahg_b2 = (const float*)d_in[30];
    const float* ahg_W3 = (const float*)d_in[31]; const float* ahg_b3 = (const float*)d_in[32];
    const float* adj_W = (const float*)d_in[33];
    const float* lnh_g = (const float*)d_in[35]; const float* lnh_b = (const float*)d_in[36];
    const float* lno_g = (const float*)d_in[37]; const float* lno_b = (const float*)d_in[38];

    char* w = (char*)d_ws;
    auto alloc = [&](size_t bytes) { char* p = w; w += (bytes + 255) & ~(size_t)255; return p; };
    bf16*  sp      = (bf16*)alloc((size_t)P_ * 1024 * 2);
    bf16*  a2_ah   = (bf16*)alloc((size_t)P_ * 1024 * 2);
    bf16*  Hbuf    = (bf16*)alloc((size_t)P_ * 1024 * 2);   // ah-head H (used twice)
    bf16*  H_o2s   = (bf16*)alloc((size_t)P_ * 1024 * 2);   // also reused for s2o H
    bf16*  H_ahg   = (bf16*)alloc((size_t)P_ * 1024 * 2);
    bf16*  spat_pad= (bf16*)alloc((size_t)P_ * 64 * 2);
    bf16*  spL1    = (bf16*)alloc((size_t)P_ * 128 * 2);
    bf16*  spL2    = (bf16*)alloc((size_t)P_ * 256 * 2);
    bf16*  enc_bf  = (bf16*)alloc(256 * 1024 * 2);
    bf16*  henc_bf = (bf16*)alloc(64 * 1024 * 2);
    bf16*  oenc_bf = (bf16*)alloc(256 * 1024 * 2);
    bf16*  spW1t   = (bf16*)alloc(128 * 64 * 2);
    bf16*  spW2t   = (bf16*)alloc(256 * 128 * 2);
    bf16*  spW3t   = (bf16*)alloc(1024 * 256 * 2);
    bf16*  W2cat   = (bf16*)alloc((size_t)3072 * 1024 * 2); // [ahW2t; o2sW2t; ahgW2t]
    bf16*  W1catB  = (bf16*)alloc((size_t)2048 * 1024 * 2); // [ahW1tB; o2sW1t]
    bf16*  W1catF  = (bf16*)alloc((size_t)2048 * 1024 * 2); // [s2oW1t; ahW1tT]
    bf16*  s2oW2t  = (bf16*)alloc(1024 * 1024 * 2);
    bf16*  ahW3t   = (bf16*)alloc(1024 * 1024 * 2);
    bf16*  o2sW3t  = (bf16*)alloc(1024 * 1024 * 2);
    bf16*  s2oW3t  = (bf16*)alloc(1024 * 1024 * 2);
    bf16*  ahgW3t  = (bf16*)alloc(1024 * 1024 * 2);
    // zero-init block 1 (contiguous): Ah | Aoa1 | A1f | Ao_f
    float* Ah    = (float*)alloc(64 * 1024 * 4);
    float* Aoa1  = (float*)alloc(256 * 2048 * 4);   // cols 0..1023 = Ao, 1024.. = a1o2s
    float* A1f   = (float*)alloc(64 * 2048 * 4);    // cols 0..1023 = a1s2o, 1024.. = Ah_f
    float* Ao_f  = (float*)alloc(256 * 1024 * 4);
    size_t z1_bytes = (size_t)(64 * 1024 + 256 * 2048 + 64 * 2048 + 256 * 1024) * 4 + 1024;
    // zero-init block 2 (contiguous): adjv | msgh | msgo
    float* adjv  = (float*)alloc(P_ * 4);
    float* msgh  = (float*)alloc(64 * 1024 * 4);
    float* msgo  = (float*)alloc(256 * 1024 * 4);
    size_t z2_bytes = (size_t)(P_ + 64 * 1024 + 256 * 1024) * 4 + 1024;
    float* sh    = (float*)alloc(P_ * 4);
    float* so    = (float*)alloc(P_ * 4);
    float* a1g   = (float*)alloc(1024 * 4);
    float* sb3_ah  = (float*)alloc(4096);
    float* sb3_o2s = (float*)alloc(4096);
    float* sb3_s2o = (float*)alloc(4096);
    float* sb3_ahg = (float*)alloc(4096);

    hipMemsetAsync(Ah,   0, z1_bytes, stream);
    hipMemsetAsync(adjv, 0, z2_bytes, stream);

    // ---- batched weight conversions
    {
        T8 t;
        t.s[0] = ah_W1;                     t.d[0] = W1catF + (size_t)1024 * 1024; t.ss[0] = (size_t)2048 * 64; // Ah^T
        t.s[1] = ah_W1 + (size_t)1024 * 64; t.d[1] = W1catB;                       t.ss[1] = (size_t)2048 * 64; // Ao^T
        t.s[2] = o2s_W1;                    t.d[2] = W1catB + (size_t)1024 * 1024; t.ss[2] = 65536;
        t.s[3] = s2o_W1;                    t.d[3] = W1catF;                       t.ss[3] = 65536;
        t.s[4] = ah_W2;                     t.d[4] = W2cat;                        t.ss[4] = 65536;
        t.s[5] = o2s_W2;                    t.d[5] = W2cat + (size_t)1024 * 1024;  t.ss[5] = 65536;
        t.s[6] = ahg_W2;                    t.d[6] = W2cat + (size_t)2048 * 1024;  t.ss[6] = 65536;
        t.s[7] = s2o_W2;                    t.d[7] = s2oW2t;                       t.ss[7] = 65536;
        transp64b<<<dim3(2, 32, 128), dim3(32, 8), 0, stream>>>(t);
    }
    {
        T4 t;
        t.s[0] = ah_W3;  t.d[0] = ahW3t;
        t.s[1] = o2s_W3; t.d[1] = o2sW3t;
        t.s[2] = s2o_W3; t.d[2] = s2oW3t;
        t.s[3] = ahg_W3; t.d[3] = ahgW3t;
        transp1024b<<<dim3(32, 32, 4), dim3(32, 8), 0, stream>>>(t);
    }
    dim3 tb(32, 8);
    conv_spw1<<<32, 256, 0, stream>>>(sp_W1, spW1t);
    transp<<<dim3(8, 4, 1),  tb, 0, stream>>>(sp_W2, spW2t, 128, 256, 0, 0);
    transp<<<dim3(32, 8, 1), tb, 0, stream>>>(sp_W3, spW3t, 256, 1024, 0, 0);
    pad_spatial<<<4096, 256, 0, stream>>>(spatial, spat_pad);
    cast_f2b<<<1024, 256, 0, stream>>>(node_enc, enc_bf, 256 * 1024);
    {
        S4 a;
        a.s[0] = ah_b3;  a.d[0] = sb3_ah;
        a.s[1] = o2s_b3; a.d[1] = sb3_o2s;
        a.s[2] = s2o_b3; a.d[2] = sb3_s2o;
        a.s[3] = ahg_b3; a.d[3] = sb3_ahg;
        sumb3b<<<16, 256, 0, stream>>>(a);
    }
    a1g_k<<<4, 256, 0, stream>>>(gfeat, ahg_W1, ahg_b1, a1g);

    // ---- small split-K GEMMs (round 1 prerequisites)
    // {Ao | a1o2s}: M=256, N=2048, B=W1catB
    gemm_bt<2, false, false><<<dim3(2, 16, 16), 256, 0, stream>>>(
        mkargs(enc_bf, W1catB, Aoa1, nullptr, nullptr, nullptr, 256, 2048, 1024, 2048, 64, 0));
    // Ah: M=64, N=1024, B=ahW1tT (= W1catF second half)
    gemm_bt<2, false, false><<<dim3(1, 8, 16), 256, 0, stream>>>(
        mkargs(enc_bf, W1catF + (size_t)1024 * 1024, Ah, nullptr, nullptr, nullptr, 64, 1024, 1024, 1024, 64, 0));

    // ---- sp MLP
    gemm_bt<1, true, true><<<dim3(128, 1), 256, 0, stream>>>(
        mkargs(spat_pad, spW1t, spL1, sp_b1, nullptr, nullptr, P_, 128, 64, 128, 0, 0));
    gemm_bt<1, true, true><<<dim3(128, 2), 256, 0, stream>>>(
        mkargs(spL1, spW2t, spL2, sp_b2, nullptr, nullptr, P_, 256, 128, 256, 0, 0));
    gemm_bt<1, true, true><<<dim3(128, 8), 256, 0, stream>>>(
        mkargs(spL2, spW3t, sp, sp_b3, nullptr, nullptr, P_, 1024, 256, 1024, 0, 0));

    // ---- merged W2 GEMM: N=3072 -> a2_ah | H_o2s | H_ahg
    {
        GArgs g = mkargs(sp, W2cat, a2_ah, nullptr, Aoa1 + 1024, nullptr, P_, 3072, 1024, 1024, 0, 2048);
        g.C2 = H_o2s; g.C3 = H_ahg;
        g.b2a = ah_b2; g.b2b = o2s_b2; g.b2c = ahg_b2; g.b1o = o2s_b1; g.a1gv = a1g;
        gemm_bt<9, false, false><<<dim3(128, 24), 256, 0, stream>>>(g);
    }

    // ---- ah-head H -> adj -> softmaxes
    hbuild<<<8192, 256, 0, stream>>>(Ah, 1024, Aoa1, 2048, ah_b1, a2_ah, Hbuf);
    gemm_bt<6, false, false><<<dim3(128, 8), 256, 0, stream>>>(
        mkargs(Hbuf, ahW3t, adjv, sb3_ah, adj_W, nullptr, P_, 1024, 1024, 1024, 0, 0));
    softmax_h<<<64, 256, 0, stream>>>(adjv, sh);
    softmax_o<<<256, 64, 0, stream>>>(adjv, so);

    // ---- msg_h -> h_enc'
    gemm_bt<7, false, false><<<dim3(128, 8), 256, 0, stream>>>(
        mkargs(H_o2s, o2sW3t, msgh, nullptr, sh, nullptr, P_, 1024, 1024, 1024, 0, 0));
    ln_k<<<64, 256, 0, stream>>>(node_enc, msgh, sb3_o2s, lnh_g, lnh_b, henc_bf);

    // ---- {a1s2o | Ah_f}: M=64, N=2048, B=W1catF
    gemm_bt<2, false, false><<<dim3(1, 16, 16), 256, 0, stream>>>(
        mkargs(henc_bf, W1catF, A1f, nullptr, nullptr, nullptr, 64, 2048, 1024, 2048, 64, 0));

    // ---- s2o a2 + fused H (permuted rows) -> msg_o -> o_enc'
    gemm_bt<4, false, false><<<dim3(128, 8), 256, 0, stream>>>(
        mkargs(sp, s2oW2t, H_o2s /*reuse as H_s2o*/, s2o_b2, A1f, s2o_b1, P_, 1024, 1024, 1024, 0, 2048));
    gemm_bt<8, false, false><<<dim3(128, 8), 256, 0, stream>>>(
        mkargs(H_o2s, s2oW3t, msgo, nullptr, so, nullptr, P_, 1024, 1024, 1024, 0, 0));
    ln_k<<<256, 256, 0, stream>>>(node_enc, msgo, sb3_s2o, lno_g, lno_b, oenc_bf);

    // ---- Ao_f, final ah-head H, f_local
    gemm_bt<2, false, false><<<dim3(2, 8, 16), 256, 0, stream>>>(
        mkargs(oenc_bf, W1catB, Ao_f, nullptr, nullptr, nullptr, 256, 1024, 1024, 1024, 64, 0));
    hbuild<<<8192, 256, 0, stream>>>(A1f + 1024, 2048, Ao_f, 1024, ah_b1, a2_ah, Hbuf);
    gemm_bt<0, true, true><<<dim3(128, 8), 256, 0, stream>>>(
        mkargs(Hbuf, ahW3t, (float*)d_out, sb3_ah, nullptr, nullptr, P_, 1024, 1024, 2048, 0, 0));

    // ---- f_glob
    gemm_bt<0, true, true><<<dim3(128, 8), 256, 0, stream>>>(
        mkargs(H_ahg, ahgW3t, (float*)d_out + 1024, sb3_ahg, nullptr, nullptr, P_, 1024, 1024, 2048, 0, 0));

    (void)in_sizes; (void)n_in; (void)out_size; (void)ws_size;
}

// Round 4
// 802.775 us; speedup vs baseline: 1.2765x; 1.0087x over previous
//
#include <hip/hip_runtime.h>
#include <hip/hip_bf16.h>
#include <stdint.h>
#include <stddef.h>

using bf16 = __hip_bfloat16;
typedef __bf16 bf16x8 __attribute__((ext_vector_type(8)));
typedef float f32x4 __attribute__((ext_vector_type(4)));

#define P_  16384

// ---------------------------------------------------------------- async g->LDS
__device__ __forceinline__ void gload16(const void* g, void* l) {
    __builtin_amdgcn_global_load_lds((const __attribute__((address_space(1))) void*)g,
                                     (__attribute__((address_space(3))) void*)l, 16, 0, 0);
}

// ---------------------------------------------------------------- GEMM (B^T)
struct GArgs {
    const bf16* A; const bf16* B; void* C;
    const float* bias;    // column bias
    const float* aux1;    // adj_W (M6)
    int M, N, K, ldc, kchunk;
    // MODE 9 extras:
    void* dst1; void* dst2; void* dst3; void* dstH;            // a2_o2s, a2_s2o, H_ahg, Hbuf
    const float* cb0; const float* cb1; const float* cb2; const float* cb3;
    const float* a1gv; const float* Ahp; const float* Aop; const float* b1p;
};

// C[M,N] = A[M,K] @ B^T, B stored N x K row-major, both bf16.
// 128x128 tile, BK=32, 4 waves 2x2, 4x4 frags of 16x16x32 MFMA.
// MODE 0: store fp32 (+bias/relu)       MODE 1: store bf16 (+bias/relu)
// MODE 2: split-K, atomicAdd fp32 (grid.z = K/kchunk)
// MODE 6: adj: atomicAdd(C[p], sum_c relu(acc+bias[c])*aux1[c])
// MODE 9: merged W2 quad: grp0 -> a2_ah bf16 + Hbuf fused; grp1 -> a2_o2s;
//         grp2 -> a2_s2o; grp3 -> H_ahg fused (a1g)
template<int MODE, bool RELU, bool BIAS>
__global__ __launch_bounds__(256, 4)
void gemm_bt(GArgs g)
{
    __shared__ __align__(16) bf16 As[128 * 32];
    __shared__ __align__(16) bf16 Bs[128 * 32];

    const int tid  = threadIdx.x;
    const int wave = tid >> 6;
    const int lane = tid & 63;
    const int tileM = blockIdx.x * 128;
    const int tileN = blockIdx.y * 128;
    const int wr = (wave >> 1) << 6;
    const int wc = (wave & 1) << 6;
    const int M = g.M, N = g.N, K = g.K;

    f32x4 acc[4][4] = {};

    int arow[2], brow[2], ako[2];
    #pragma unroll
    for (int j = 0; j < 2; ++j) {
        int c  = wave * 128 + j * 64 + lane;
        int r  = c >> 2;
        ako[j] = (c & 3) << 3;
        int gr = tileM + r; if (gr > M - 1) gr = M - 1;
        arow[j] = gr;
        int gn = tileN + r; if (gn > N - 1) gn = N - 1;
        brow[j] = gn;
    }
    const int m0   = wr + (lane & 15);
    const int n0   = wc + (lane & 15);
    const int koff = (lane >> 4) << 3;

    int kbeg = 0, kend = K;
    if constexpr (MODE == 2) { kbeg = blockIdx.z * g.kchunk; kend = kbeg + g.kchunk; }

    for (int k0 = kbeg; k0 < kend; k0 += 32) {
        #pragma unroll
        for (int j = 0; j < 2; ++j) {
            int c = wave * 128 + j * 64 + lane;
            gload16(g.A + (size_t)arow[j] * K + k0 + ako[j], (void*)(As + c * 8));
            gload16(g.B + (size_t)brow[j] * K + k0 + ako[j], (void*)(Bs + c * 8));
        }
        __syncthreads();
        bf16x8 af[4], bfv[4];
        #pragma unroll
        for (int i = 0; i < 4; ++i) {
            af[i]  = *(const bf16x8*)(As + (m0 + i * 16) * 32 + koff);
            bfv[i] = *(const bf16x8*)(Bs + (n0 + i * 16) * 32 + koff);
        }
        #pragma unroll
        for (int i = 0; i < 4; ++i)
            #pragma unroll
            for (int j = 0; j < 4; ++j)
                acc[i][j] = __builtin_amdgcn_mfma_f32_16x16x32_bf16(af[i], bfv[j], acc[i][j], 0, 0, 0);
        __syncthreads();
    }

    const int rbase = tileM + wr + ((lane >> 4) << 2);
    const int cbase = tileN + wc + (lane & 15);

    if constexpr (MODE == 0 || MODE == 1) {
        #pragma unroll
        for (int i = 0; i < 4; ++i)
            #pragma unroll
            for (int j = 0; j < 4; ++j)
                #pragma unroll
                for (int r = 0; r < 4; ++r) {
                    int grow = rbase + i * 16 + r;
                    if (grow >= M) continue;
                    int gcol = cbase + j * 16;
                    float v = acc[i][j][r];
                    if (BIAS) v += g.bias[gcol];
                    if (RELU) v = fmaxf(v, 0.f);
                    if (MODE == 1) ((bf16*)g.C)[(size_t)grow * g.ldc + gcol] = __float2bfloat16(v);
                    else           ((float*)g.C)[(size_t)grow * g.ldc + gcol] = v;
                }
    } else if constexpr (MODE == 2) {
        #pragma unroll
        for (int i = 0; i < 4; ++i)
            #pragma unroll
            for (int j = 0; j < 4; ++j)
                #pragma unroll
                for (int r = 0; r < 4; ++r) {
                    int grow = rbase + i * 16 + r;
                    if (grow >= M) continue;
                    atomicAdd((float*)g.C + (size_t)grow * g.ldc + cbase + j * 16, acc[i][j][r]);
                }
    } else if constexpr (MODE == 6) {
        #pragma unroll
        for (int i = 0; i < 4; ++i)
            #pragma unroll
            for (int r = 0; r < 4; ++r) {
                float s = 0.f;
                #pragma unroll
                for (int j = 0; j < 4; ++j) {
                    int gcol = cbase + j * 16;
                    s += fmaxf(acc[i][j][r] + g.bias[gcol], 0.f) * g.aux1[gcol];
                }
                s += __shfl_xor(s, 1); s += __shfl_xor(s, 2);
                s += __shfl_xor(s, 4); s += __shfl_xor(s, 8);
                if ((lane & 15) == 0)
                    atomicAdd((float*)g.C + rbase + i * 16 + r, s);
            }
    } else if constexpr (MODE == 9) {
        int grp = tileN >> 10;
        int lcb = (tileN & 1023) + wc + (lane & 15);
        #pragma unroll
        for (int i = 0; i < 4; ++i)
            #pragma unroll
            for (int j = 0; j < 4; ++j)
                #pragma unroll
                for (int r = 0; r < 4; ++r) {
                    int p    = rbase + i * 16 + r;
                    int lcol = lcb + j * 16;
                    float accv = acc[i][j][r];
                    if (grp == 0) {
                        bf16 a2b = __float2bfloat16(accv + g.cb0[lcol]);
                        ((bf16*)g.C)[(size_t)p * 1024 + lcol] = a2b;
                        float a1 = g.Ahp[((size_t)(p >> 8)) * 1024 + lcol]
                                 + g.Aop[((size_t)(p & 255)) * 2048 + lcol] + g.b1p[lcol];
                        ((bf16*)g.dstH)[(size_t)p * 1024 + lcol] =
                            __float2bfloat16(fmaxf(a1 * (float)a2b, 0.f));
                    } else if (grp == 1) {
                        ((bf16*)g.dst1)[(size_t)p * 1024 + lcol] =
                            __float2bfloat16(accv + g.cb1[lcol]);
                    } else if (grp == 2) {
                        ((bf16*)g.dst2)[(size_t)p * 1024 + lcol] =
                            __float2bfloat16(accv + g.cb2[lcol]);
                    } else {
                        float a2v = accv + g.cb3[lcol];
                        ((bf16*)g.dst3)[(size_t)p * 1024 + lcol] =
                            __float2bfloat16(fmaxf(g.a1gv[lcol] * a2v, 0.f));
                    }
                }
    }
}

static GArgs mkargs(const bf16* A, const bf16* B, void* C, const float* bias,
                    const float* aux1, int M, int N, int K, int ldc, int kchunk)
{
    GArgs g{};
    g.A = A; g.B = B; g.C = C; g.bias = bias; g.aux1 = aux1;
    g.M = M; g.N = N; g.K = K; g.ldc = ldc; g.kchunk = kchunk;
    return g;
}

// ---------------------------------------------------------------- reductions over H
// HredH[h,c] = sum_n sh[h,n] * relu((a1[n,c]+b1[c]) * a2[(h*256+n),c])
// grid (4 cq, 64 h), block 256 = 8 ng x 32 ct
__global__ void reduce_o2s(const bf16* __restrict__ a2, const float* __restrict__ a1,
                           const float* __restrict__ b1, const float* __restrict__ sh,
                           bf16* __restrict__ out)
{
    int h = blockIdx.y, cq = blockIdx.x;
    int ng = threadIdx.x >> 5, ct = threadIdx.x & 31;
    int c = cq * 256 + ct * 8;
    float b1v[8], accv[8] = {};
    #pragma unroll
    for (int j = 0; j < 8; ++j) b1v[j] = b1[c + j];
    const float* shh = sh + h * 256;
    for (int n = ng; n < 256; n += 8) {
        float w = shh[n];
        bf16x8 a2v = *(const bf16x8*)(a2 + ((size_t)(h * 256 + n) << 10) + c);
        const float* a1p = a1 + (size_t)n * 2048 + c;
        #pragma unroll
        for (int j = 0; j < 8; ++j)
            accv[j] += w * fmaxf((a1p[j] + b1v[j]) * (float)a2v[j], 0.f);
    }
    __shared__ float red[8][264];
    #pragma unroll
    for (int j = 0; j < 8; ++j) red[ng][ct * 8 + j] = accv[j];
    __syncthreads();
    for (int s = 4; s > 0; s >>= 1) {
        if (ng < s)
            #pragma unroll
            for (int j = 0; j < 8; ++j) red[ng][ct * 8 + j] += red[ng + s][ct * 8 + j];
        __syncthreads();
    }
    if (ng == 0) {
        bf16x8 o;
        #pragma unroll
        for (int j = 0; j < 8; ++j) o[j] = (__bf16)red[0][ct * 8 + j];
        *(bf16x8*)(out + (size_t)h * 1024 + c) = o;
    }
}

// HredO[n,c] = sum_h so[n,h] * relu((a1[h,c]+b1[c]) * a2[(h*256+n),c])
// grid (4 cq, 256 n), block 256 = 8 hg x 32 ct
__global__ void reduce_s2o(const bf16* __restrict__ a2, const float* __restrict__ a1,
                           const float* __restrict__ b1, const float* __restrict__ so,
                           bf16* __restrict__ out)
{
    int n = blockIdx.y, cq = blockIdx.x;
    int hg = threadIdx.x >> 5, ct = threadIdx.x & 31;
    int c = cq * 256 + ct * 8;
    float b1v[8], accv[8] = {};
    #pragma unroll
    for (int j = 0; j < 8; ++j) b1v[j] = b1[c + j];
    const float* son = so + n * 64;
    #pragma unroll
    for (int hh = 0; hh < 8; ++hh) {
        int h = hg + hh * 8;
        float w = son[h];
        bf16x8 a2v = *(const bf16x8*)(a2 + ((size_t)(h * 256 + n) << 10) + c);
        const float* a1p = a1 + (size_t)h * 2048 + c;
        #pragma unroll
        for (int j = 0; j < 8; ++j)
            accv[j] += w * fmaxf((a1p[j] + b1v[j]) * (float)a2v[j], 0.f);
    }
    __shared__ float red[8][264];
    #pragma unroll
    for (int j = 0; j < 8; ++j) red[hg][ct * 8 + j] = accv[j];
    __syncthreads();
    for (int s = 4; s > 0; s >>= 1) {
        if (hg < s)
            #pragma unroll
            for (int j = 0; j < 8; ++j) red[hg][ct * 8 + j] += red[hg + s][ct * 8 + j];
        __syncthreads();
    }
    if (hg == 0) {
        bf16x8 o;
        #pragma unroll
        for (int j = 0; j < 8; ++j) o[j] = (__bf16)red[0][ct * 8 + j];
        *(bf16x8*)(out + (size_t)n * 1024 + c) = o;
    }
}

// ---------------------------------------------------------------- transposes
__global__ void transp(const float* __restrict__ src, bf16* __restrict__ dst,
                       int rows, int cols, size_t sstride, size_t dstride)
{
    const float* s = src + blockIdx.z * sstride;
    bf16*        d = dst + blockIdx.z * dstride;
    __shared__ float tile[32][33];
    int c0 = blockIdx.x * 32, r0 = blockIdx.y * 32;
    int x = threadIdx.x, y = threadIdx.y;   // (32, 8)
    for (int yy = y; yy < 32; yy += 8) {
        int r = r0 + yy, c = c0 + x;
        tile[yy][x] = (r < rows && c < cols) ? s[(size_t)r * cols + c] : 0.f;
    }
    __syncthreads();
    for (int yy = y; yy < 32; yy += 8) {
        int c = c0 + yy, r = r0 + x;
        if (c < cols && r < rows) d[(size_t)c * rows + r] = __float2bfloat16(tile[x][yy]);
    }
}

struct T8 { const float* s[8]; bf16* d[8]; size_t ss[8]; };
__global__ void transp64b(T8 t)
{
    int pair = blockIdx.z >> 4, slice = blockIdx.z & 15;
    const float* s = t.s[pair] + slice * t.ss[pair];
    bf16*        d = t.d[pair] + slice * 65536;
    __shared__ float tile[32][33];
    int c0 = blockIdx.x * 32, r0 = blockIdx.y * 32;
    int x = threadIdx.x, y = threadIdx.y;
    for (int yy = y; yy < 32; yy += 8)
        tile[yy][x] = s[(size_t)(r0 + yy) * 64 + c0 + x];
    __syncthreads();
    for (int yy = y; yy < 32; yy += 8)
        d[(size_t)(c0 + yy) * 1024 + r0 + x] = __float2bfloat16(tile[x][yy]);
}

struct T4 { const float* s[4]; bf16* d[4]; };
__global__ void transp1024b(T4 t)
{
    const float* s = t.s[blockIdx.z];
    bf16*        d = t.d[blockIdx.z];
    __shared__ float tile[32][33];
    int c0 = blockIdx.x * 32, r0 = blockIdx.y * 32;
    int x = threadIdx.x, y = threadIdx.y;
    for (int yy = y; yy < 32; yy += 8)
        tile[yy][x] = s[(size_t)(r0 + yy) * 1024 + c0 + x];
    __syncthreads();
    for (int yy = y; yy < 32; yy += 8)
        d[(size_t)(c0 + yy) * 1024 + r0 + x] = __float2bfloat16(tile[x][yy]);
}

__global__ void conv_spw1(const float* __restrict__ src, bf16* __restrict__ dst) {
    int i = blockIdx.x * 256 + threadIdx.x;
    if (i >= 128 * 64) return;
    int k = i & 63, n = i >> 6;
    dst[i] = __float2bfloat16(k < 36 ? src[k * 128 + n] : 0.f);
}

__global__ void pad_spatial(const float* __restrict__ src, bf16* __restrict__ dst) {
    int i = blockIdx.x * 256 + threadIdx.x;
    int k = i & 63, p = i >> 6;
    dst[i] = __float2bfloat16(k < 36 ? src[p * 36 + k] : 0.f);
}

__global__ void cast_f2b(const float* __restrict__ src, bf16* __restrict__ dst, int n) {
    int i = blockIdx.x * 256 + threadIdx.x;
    if (i < n) dst[i] = __float2bfloat16(src[i]);
}

struct S4 { const float* s[4]; float* d[4]; };
__global__ void sumb3b(S4 a) {
    int i = blockIdx.x * 256 + threadIdx.x;
    int pair = i >> 10, r = i & 1023;
    const float* b3 = a.s[pair];
    float s = 0.f;
    #pragma unroll
    for (int c = 0; c < 16; ++c) s += b3[c * 1024 + r];
    a.d[pair][r] = s;
}

// H = relu((Ah[p>>8] + Ao[p&255] + b1) * a2)
__global__ void hbuild(const float* __restrict__ Ah, int ah_ld,
                       const float* __restrict__ Ao, int ao_ld,
                       const float* __restrict__ b1, const bf16* __restrict__ a2,
                       bf16* __restrict__ H)
{
    size_t base = ((size_t)blockIdx.x * 256 + threadIdx.x) * 8;
    int cs = (int)(base & 1023);
    int p  = (int)(base >> 10);
    const float* ph = Ah + (size_t)(p >> 8) * ah_ld + cs;
    const float* po = Ao + (size_t)(p & 255) * ao_ld + cs;
    bf16x8 av = *(const bf16x8*)(a2 + base);
    bf16x8 o;
    #pragma unroll
    for (int j = 0; j < 8; ++j) {
        float a1 = ph[j] + po[j] + b1[cs + j];
        o[j] = (__bf16)fmaxf(a1 * (float)av[j], 0.f);
    }
    *(bf16x8*)(H + base) = o;
}

// ---------------------------------------------------------------- softmax / LN
__global__ void softmax_h(const float* __restrict__ adj, float* __restrict__ sh) {
    int h = blockIdx.x, n = threadIdx.x;
    __shared__ float red[256];
    float v = adj[h * 256 + n];
    red[n] = v; __syncthreads();
    for (int s = 128; s > 0; s >>= 1) { if (n < s) red[n] = fmaxf(red[n], red[n + s]); __syncthreads(); }
    float m = red[0]; __syncthreads();
    float e = expf(v - m);
    red[n] = e; __syncthreads();
    for (int s = 128; s > 0; s >>= 1) { if (n < s) red[n] += red[n + s]; __syncthreads(); }
    sh[h * 256 + n] = e / red[0];
}

__global__ void softmax_o(const float* __restrict__ adj, float* __restrict__ so) {
    int n = blockIdx.x, h = threadIdx.x;
    float v = adj[h * 256 + n];
    float m = v;
    #pragma unroll
    for (int off = 32; off; off >>= 1) m = fmaxf(m, __shfl_xor(m, off));
    float e = expf(v - m);
    float s = e;
    #pragma unroll
    for (int off = 32; off; off >>= 1) s += __shfl_xor(s, off);
    so[n * 64 + h] = e / s;
}

__global__ void ln_k(const float* __restrict__ x, const float* __restrict__ msgraw,
                     const float* __restrict__ sb3,
                     const float* __restrict__ g, const float* __restrict__ bb,
                     bf16* __restrict__ out)
{
    int row = blockIdx.x, t = threadIdx.x;
    const float* xr = x + (size_t)row * 1024;
    const float* mr = msgraw + (size_t)row * 1024;
    float v[4]; float s = 0.f, ss = 0.f;
    #pragma unroll
    for (int j = 0; j < 4; ++j) {
        int i = t + j * 256;
        v[j] = xr[i] + fmaxf(mr[i] + sb3[i], 0.f);
        s += v[j]; ss += v[j] * v[j];
    }
    __shared__ float r1[256], r2[256];
    r1[t] = s; r2[t] = ss; __syncthreads();
    for (int k = 128; k > 0; k >>= 1) { if (t < k) { r1[t] += r1[t + k]; r2[t] += r2[t + k]; } __syncthreads(); }
    float mean = r1[0] * (1.f / 1024.f);
    float var  = r2[0] * (1.f / 1024.f) - mean * mean;
    float inv  = rsqrtf(var + 1e-5f);
    #pragma unroll
    for (int j = 0; j < 4; ++j) {
        int i = t + j * 256;
        out[(size_t)row * 1024 + i] = __float2bfloat16((v[j] - mean) * inv * g[i] + bb[i]);
    }
}

__global__ void a1g_k(const float* __restrict__ gf, const float* __restrict__ W1,
                      const float* __restrict__ b1, float* __restrict__ a1g)
{
    int cs = blockIdx.x * 256 + threadIdx.x;
    int c = cs >> 6, s = cs & 63;
    float acc = b1[cs];
    for (int g = 0; g < 256; ++g) acc += gf[g] * W1[((size_t)c * 256 + g) * 64 + s];
    a1g[cs] = acc;
}

// ---------------------------------------------------------------- launch
extern "C" void kernel_launch(void* const* d_in, const int* in_sizes, int n_in,
                              void* d_out, int out_size, void* d_ws, size_t ws_size,
                              hipStream_t stream)
{
    const float* node_enc = (const float*)d_in[0];
    const float* spatial  = (const float*)d_in[1];
    const float* gfeat    = (const float*)d_in[2];
    const float* sp_W1 = (const float*)d_in[3];  const float* sp_b1 = (const float*)d_in[4];
    const float* sp_W2 = (const float*)d_in[5];  const float* sp_b2 = (const float*)d_in[6];
    const float* sp_W3 = (const float*)d_in[7];  const float* sp_b3 = (const float*)d_in[8];
    const float* ah_W1 = (const float*)d_in[9];  const float* ah_b1 = (const float*)d_in[10];
    const float* ah_W2 = (const float*)d_in[11]; const float* ah_b2 = (const float*)d_in[12];
    const float* ah_W3 = (const float*)d_in[13]; const float* ah_b3 = (const float*)d_in[14];
    const float* o2s_W1 = (const float*)d_in[15]; const float* o2s_b1 = (const float*)d_in[16];
    const float* o2s_W2 = (const float*)d_in[17]; const float* o2s_b2 = (const float*)d_in[18];
    const float* o2s_W3 = (const float*)d_in[19]; const float* o2s_b3 = (const float*)d_in[20];
    const float* s2o_W1 = (const float*)d_in[21]; const float* s2o_b1 = (const float*)d_in[22];
    const float* s2o_W2 = (const float*)d_in[23]; const float* s2o_b2 = (const float*)d_in[24];
    const float* s2o_W3 = (const float*)d_in[25]; const float* s2o_b3 = (const float*)d_in[26];
    const float* ahg_W1 = (const float*)d_in[27]; const float* ahg_b1 = (const float*)d_in[28];
    const float* ahg_W2 = (const float*)d_in[29]; const float* ahg_b2 = (const float*)d_in[30];
    const float* ahg_W3 = (const float*)d_in[31]; const float* ahg_b3 = (const float*)d_in[32];
    const float* adj_W = (const float*)d_in[33];
    const float* lnh_g = (const float*)d_in[35]; const float* lnh_b = (const float*)d_in[36];
    const float* lno_g = (const float*)d_in[37]; const float* lno_b = (const float*)d_in[38];

    char* w = (char*)d_ws;
    auto alloc = [&](size_t bytes) { char* p = w; w += (bytes + 255) & ~(size_t)255; return p; };
    bf16*  sp      = (bf16*)alloc((size_t)P_ * 1024 * 2);
    bf16*  a2_ah   = (bf16*)alloc((size_t)P_ * 1024 * 2);
    bf16*  Hbuf    = (bf16*)alloc((size_t)P_ * 1024 * 2);
    bf16*  a2_o2s  = (bf16*)alloc((size_t)P_ * 1024 * 2);
    bf16*  a2_s2o  = (bf16*)alloc((size_t)P_ * 1024 * 2);
    bf16*  H_ahg   = (bf16*)alloc((size_t)P_ * 1024 * 2);
    bf16*  spat_pad= (bf16*)alloc((size_t)P_ * 64 * 2);
    bf16*  spL1    = (bf16*)alloc((size_t)P_ * 128 * 2);
    bf16*  spL2    = (bf16*)alloc((size_t)P_ * 256 * 2);
    bf16*  enc_bf  = (bf16*)alloc(256 * 1024 * 2);
    bf16*  henc_bf = (bf16*)alloc(64 * 1024 * 2);
    bf16*  oenc_bf = (bf16*)alloc(256 * 1024 * 2);
    bf16*  HredH   = (bf16*)alloc(64 * 1024 * 2);
    bf16*  HredO   = (bf16*)alloc(256 * 1024 * 2);
    bf16*  spW1t   = (bf16*)alloc(128 * 64 * 2);
    bf16*  spW2t   = (bf16*)alloc(256 * 128 * 2);
    bf16*  spW3t   = (bf16*)alloc(1024 * 256 * 2);
    bf16*  W2cat   = (bf16*)alloc((size_t)4096 * 1024 * 2); // [ah; o2s; s2o; ahg]
    bf16*  W1catB  = (bf16*)alloc((size_t)2048 * 1024 * 2); // [ahW1tB; o2sW1t]
    bf16*  W1catF  = (bf16*)alloc((size_t)2048 * 1024 * 2); // [s2oW1t; ahW1tT]
    bf16*  ahW3t   = (bf16*)alloc(1024 * 1024 * 2);
    bf16*  o2sW3t  = (bf16*)alloc(1024 * 1024 * 2);
    bf16*  s2oW3t  = (bf16*)alloc(1024 * 1024 * 2);
    bf16*  ahgW3t  = (bf16*)alloc(1024 * 1024 * 2);
    // zero-init block 1: Ah | Aoa1 | A1f | Ao_f
    float* Ah    = (float*)alloc(64 * 1024 * 4);
    float* Aoa1  = (float*)alloc(256 * 2048 * 4);
    float* A1f   = (float*)alloc(64 * 2048 * 4);
    float* Ao_f  = (float*)alloc(256 * 1024 * 4);
    size_t z1_bytes = (size_t)(64 * 1024 + 256 * 2048 + 64 * 2048 + 256 * 1024) * 4 + 1024;
    // zero-init block 2: adjv | msgh | msgo
    float* adjv  = (float*)alloc(P_ * 4);
    float* msgh  = (float*)alloc(64 * 1024 * 4);
    float* msgo  = (float*)alloc(256 * 1024 * 4);
    size_t z2_bytes = (size_t)(P_ + 64 * 1024 + 256 * 1024) * 4 + 1024;
    float* sh    = (float*)alloc(P_ * 4);
    float* so    = (float*)alloc(P_ * 4);
    float* a1g   = (float*)alloc(1024 * 4);
    float* sb3_ah  = (float*)alloc(4096);
    float* sb3_o2s = (float*)alloc(4096);
    float* sb3_s2o = (float*)alloc(4096);
    float* sb3_ahg = (float*)alloc(4096);

    hipMemsetAsync(Ah,   0, z1_bytes, stream);
    hipMemsetAsync(adjv, 0, z2_bytes, stream);

    // ---- batched weight conversions
    {
        T8 t;
        t.s[0] = ah_W1;                     t.d[0] = W1catF + (size_t)1024 * 1024; t.ss[0] = (size_t)2048 * 64;
        t.s[1] = ah_W1 + (size_t)1024 * 64; t.d[1] = W1catB;                       t.ss[1] = (size_t)2048 * 64;
        t.s[2] = o2s_W1;                    t.d[2] = W1catB + (size_t)1024 * 1024; t.ss[2] = 65536;
        t.s[3] = s2o_W1;                    t.d[3] = W1catF;                       t.ss[3] = 65536;
        t.s[4] = ah_W2;                     t.d[4] = W2cat;                        t.ss[4] = 65536;
        t.s[5] = o2s_W2;                    t.d[5] = W2cat + (size_t)1024 * 1024;  t.ss[5] = 65536;
        t.s[6] = s2o_W2;                    t.d[6] = W2cat + (size_t)2048 * 1024;  t.ss[6] = 65536;
        t.s[7] = ahg_W2;                    t.d[7] = W2cat + (size_t)3072 * 1024;  t.ss[7] = 65536;
        transp64b<<<dim3(2, 32, 128), dim3(32, 8), 0, stream>>>(t);
    }
    {
        T4 t;
        t.s[0] = ah_W3;  t.d[0] = ahW3t;
        t.s[1] = o2s_W3; t.d[1] = o2sW3t;
        t.s[2] = s2o_W3; t.d[2] = s2oW3t;
        t.s[3] = ahg_W3; t.d[3] = ahgW3t;
        transp1024b<<<dim3(32, 32, 4), dim3(32, 8), 0, stream>>>(t);
    }
    dim3 tb(32, 8);
    conv_spw1<<<32, 256, 0, stream>>>(sp_W1, spW1t);
    transp<<<dim3(8, 4, 1),  tb, 0, stream>>>(sp_W2, spW2t, 128, 256, 0, 0);
    transp<<<dim3(32, 8, 1), tb, 0, stream>>>(sp_W3, spW3t, 256, 1024, 0, 0);
    pad_spatial<<<4096, 256, 0, stream>>>(spatial, spat_pad);
    cast_f2b<<<1024, 256, 0, stream>>>(node_enc, enc_bf, 256 * 1024);
    {
        S4 a;
        a.s[0] = ah_b3;  a.d[0] = sb3_ah;
        a.s[1] = o2s_b3; a.d[1] = sb3_o2s;
        a.s[2] = s2o_b3; a.d[2] = sb3_s2o;
        a.s[3] = ahg_b3; a.d[3] = sb3_ahg;
        sumb3b<<<16, 256, 0, stream>>>(a);
    }
    a1g_k<<<4, 256, 0, stream>>>(gfeat, ahg_W1, ahg_b1, a1g);

    // ---- small split-K GEMMs
    gemm_bt<2, false, false><<<dim3(2, 16, 16), 256, 0, stream>>>(
        mkargs(enc_bf, W1catB, Aoa1, nullptr, nullptr, 256, 2048, 1024, 2048, 64));
    gemm_bt<2, false, false><<<dim3(1, 8, 16), 256, 0, stream>>>(
        mkargs(enc_bf, W1catF + (size_t)1024 * 1024, Ah, nullptr, nullptr, 64, 1024, 1024, 1024, 64));

    // ---- sp MLP
    gemm_bt<1, true, true><<<dim3(128, 1), 256, 0, stream>>>(
        mkargs(spat_pad, spW1t, spL1, sp_b1, nullptr, P_, 128, 64, 128, 0));
    gemm_bt<1, true, true><<<dim3(128, 2), 256, 0, stream>>>(
        mkargs(spL1, spW2t, spL2, sp_b2, nullptr, P_, 256, 128, 256, 0));
    gemm_bt<1, true, true><<<dim3(128, 8), 256, 0, stream>>>(
        mkargs(spL2, spW3t, sp, sp_b3, nullptr, P_, 1024, 256, 1024, 0));

    // ---- merged W2 GEMM: N=4096 -> a2_ah+Hbuf | a2_o2s | a2_s2o | H_ahg
    {
        GArgs g = mkargs(sp, W2cat, a2_ah, nullptr, nullptr, P_, 4096, 1024, 1024, 0);
        g.dst1 = a2_o2s; g.dst2 = a2_s2o; g.dst3 = H_ahg; g.dstH = Hbuf;
        g.cb0 = ah_b2; g.cb1 = o2s_b2; g.cb2 = s2o_b2; g.cb3 = ahg_b2;
        g.a1gv = a1g; g.Ahp = Ah; g.Aop = Aoa1; g.b1p = ah_b1;
        gemm_bt<9, false, false><<<dim3(128, 32), 256, 0, stream>>>(g);
    }

    // ---- adj -> softmaxes
    gemm_bt<6, false, false><<<dim3(128, 8), 256, 0, stream>>>(
        mkargs(Hbuf, ahW3t, adjv, sb3_ah, adj_W, P_, 1024, 1024, 1024, 0));
    softmax_h<<<64, 256, 0, stream>>>(adjv, sh);
    softmax_o<<<256, 64, 0, stream>>>(adjv, so);

    // ---- msg_h = Hred_h @ o2sW3 -> h_enc'
    reduce_o2s<<<dim3(4, 64), 256, 0, stream>>>(a2_o2s, Aoa1 + 1024, o2s_b1, sh, HredH);
    gemm_bt<2, false, false><<<dim3(1, 8, 16), 256, 0, stream>>>(
        mkargs(HredH, o2sW3t, msgh, nullptr, nullptr, 64, 1024, 1024, 1024, 64));
    ln_k<<<64, 256, 0, stream>>>(node_enc, msgh, sb3_o2s, lnh_g, lnh_b, henc_bf);

    // ---- {a1s2o | Ah_f}
    gemm_bt<2, false, false><<<dim3(1, 16, 16), 256, 0, stream>>>(
        mkargs(henc_bf, W1catF, A1f, nullptr, nullptr, 64, 2048, 1024, 2048, 64));

    // ---- msg_o = Hred_o @ s2oW3 -> o_enc'
    reduce_s2o<<<dim3(4, 256), 256, 0, stream>>>(a2_s2o, A1f, s2o_b1, so, HredO);
    gemm_bt<2, false, false><<<dim3(2, 8, 16), 256, 0, stream>>>(
        mkargs(HredO, s2oW3t, msgo, nullptr, nullptr, 256, 1024, 1024, 1024, 64));
    ln_k<<<256, 256, 0, stream>>>(node_enc, msgo, sb3_s2o, lno_g, lno_b, oenc_bf);

    // ---- Ao_f, final ah-head H, f_local
    gemm_bt<2, false, false><<<dim3(2, 8, 16), 256, 0, stream>>>(
        mkargs(oenc_bf, W1catB, Ao_f, nullptr, nullptr, 256, 1024, 1024, 1024, 64));
    hbuild<<<8192, 256, 0, stream>>>(A1f + 1024, 2048, Ao_f, 1024, ah_b1, a2_ah, Hbuf);
    gemm_bt<0, true, true><<<dim3(128, 8), 256, 0, stream>>>(
        mkargs(Hbuf, ahW3t, (float*)d_out, sb3_ah, nullptr, P_, 1024, 1024, 2048, 0));

    // ---- f_glob
    gemm_bt<0, true, true><<<dim3(128, 8), 256, 0, stream>>>(
        mkargs(H_ahg, ahgW3t, (float*)d_out + 1024, sb3_ahg, nullptr, P_, 1024, 1024, 2048, 0));

    (void)in_sizes; (void)n_in; (void)out_size; (void)ws_size;
}

// Round 5
// 795.823 us; speedup vs baseline: 1.2876x; 1.0087x over previous
//
#include <hip/hip_runtime.h>
#include <hip/hip_bf16.h>
#include <stdint.h>
#include <stddef.h>

using bf16 = __hip_bfloat16;
typedef __bf16 bf16x8 __attribute__((ext_vector_type(8)));
typedef float f32x4 __attribute__((ext_vector_type(4)));

#define P_  16384

// ---------------------------------------------------------------- async g->LDS
__device__ __forceinline__ void gload16(const void* g, void* l) {
    __builtin_amdgcn_global_load_lds((const __attribute__((address_space(1))) void*)g,
                                     (__attribute__((address_space(3))) void*)l, 16, 0, 0);
}

// ---------------------------------------------------------------- GEMM (B^T)
struct GArgs {
    const bf16* A; const bf16* B; void* C;
    const float* bias;    // column bias
    const float* aux1;    // adj_W (M6)
    int M, N, K, ldc, kchunk;
    // MODE 9 extras / MODE 0 dual (z=1) pointers:
    void* dst1; void* dst2; void* dst3; void* dstH;
    const float* cb0; const float* cb1; const float* cb2; const float* cb3;
    const float* a1gv; const float* Ahp; const float* Aop; const float* b1p;
};

// C[M,N] = A[M,K] @ B^T, B stored N x K row-major, both bf16.
// 128x128 tile, BK=64, XOR-swizzled LDS (slot = g ^ (row&7)), 4 waves 2x2,
// 4x4 frags of 16x16x32 MFMA.
// MODE 0: store fp32 (+bias/relu); grid.z==1 switches to {dst1,dst2,dst3,cb1}
// MODE 1: store bf16 (+bias/relu)
// MODE 2: split-K (kchunk=64), atomicAdd fp32, grid.z = K/64
// MODE 6: adj: atomicAdd(C[p], sum_c relu(acc+bias[c])*aux1[c])
// MODE 9: merged W2 quad: grp0 -> a2_ah bf16 + Hbuf fused; grp1 -> a2_o2s;
//         grp2 -> a2_s2o; grp3 -> H_ahg fused (a1g)
template<int MODE, bool RELU, bool BIAS>
__global__ __launch_bounds__(256, 4)
void gemm_bt(GArgs g)
{
    __shared__ __align__(16) bf16 As[128 * 64];
    __shared__ __align__(16) bf16 Bs[128 * 64];

    const int tid  = threadIdx.x;
    const int wave = tid >> 6;
    const int lane = tid & 63;
    const int tileM = blockIdx.x * 128;
    const int tileN = blockIdx.y * 128;
    const int wr = (wave >> 1) << 6;
    const int wc = (wave & 1) << 6;
    const int M = g.M, N = g.N, K = g.K;

    const bf16* Ap = g.A; const bf16* Bp = g.B;
    void* Cp = g.C; const float* biasp = g.bias;
    if (MODE == 0 && blockIdx.z == 1) {
        Ap = (const bf16*)g.dst1; Bp = (const bf16*)g.dst2;
        Cp = g.dst3; biasp = g.cb1;
    }

    f32x4 acc[4][4] = {};

    // staging: chunk c = wave*256 + j*64 + lane; row = c>>3; slot = c&7;
    // slot holds k-group g = slot ^ (row&7). For this thread:
    //   row&7 = lane>>3, slot = lane&7  ->  g = (lane&7)^(lane>>3)
    const int gk = (((lane & 7) ^ (lane >> 3)) << 3);   // k elem offset 0..56
    int arow[4], brow[4];
    #pragma unroll
    for (int j = 0; j < 4; ++j) {
        int r = wave * 32 + j * 8 + (lane >> 3);
        int gr = tileM + r; if (gr > M - 1) gr = M - 1; arow[j] = gr;
        int gn = tileN + r; if (gn > N - 1) gn = N - 1; brow[j] = gn;
    }
    const int m0 = wr + (lane & 15);
    const int n0 = wc + (lane & 15);
    const int q  = lane >> 4;

    int kbeg = 0, kend = K;
    if constexpr (MODE == 2) { kbeg = blockIdx.z * 64; kend = kbeg + 64; }

    for (int k0 = kbeg; k0 < kend; k0 += 64) {
        #pragma unroll
        for (int j = 0; j < 4; ++j) {
            int c = wave * 256 + j * 64 + lane;
            gload16(Ap + (size_t)arow[j] * K + k0 + gk, (void*)(As + c * 8));
            gload16(Bp + (size_t)brow[j] * K + k0 + gk, (void*)(Bs + c * 8));
        }
        __syncthreads();
        #pragma unroll
        for (int kk = 0; kk < 2; ++kk) {
            // fragment k-group g = kk*4 + q; LDS slot = g ^ (row&7); row&7 = lane&7
            const int gs = ((kk << 2) + q) ^ (lane & 7);
            bf16x8 af[4], bfv[4];
            #pragma unroll
            for (int i = 0; i < 4; ++i) {
                af[i]  = *(const bf16x8*)(As + (m0 + i * 16) * 64 + gs * 8);
                bfv[i] = *(const bf16x8*)(Bs + (n0 + i * 16) * 64 + gs * 8);
            }
            #pragma unroll
            for (int i = 0; i < 4; ++i)
                #pragma unroll
                for (int j = 0; j < 4; ++j)
                    acc[i][j] = __builtin_amdgcn_mfma_f32_16x16x32_bf16(af[i], bfv[j], acc[i][j], 0, 0, 0);
        }
        __syncthreads();
    }

    const int rbase = tileM + wr + ((lane >> 4) << 2);
    const int cbase = tileN + wc + (lane & 15);

    if constexpr (MODE == 0 || MODE == 1) {
        #pragma unroll
        for (int i = 0; i < 4; ++i)
            #pragma unroll
            for (int j = 0; j < 4; ++j)
                #pragma unroll
                for (int r = 0; r < 4; ++r) {
                    int grow = rbase + i * 16 + r;
                    if (grow >= M) continue;
                    int gcol = cbase + j * 16;
                    float v = acc[i][j][r];
                    if (BIAS) v += biasp[gcol];
                    if (RELU) v = fmaxf(v, 0.f);
                    if (MODE == 1) ((bf16*)Cp)[(size_t)grow * g.ldc + gcol] = __float2bfloat16(v);
                    else           ((float*)Cp)[(size_t)grow * g.ldc + gcol] = v;
                }
    } else if constexpr (MODE == 2) {
        #pragma unroll
        for (int i = 0; i < 4; ++i)
            #pragma unroll
            for (int j = 0; j < 4; ++j)
                #pragma unroll
                for (int r = 0; r < 4; ++r) {
                    int grow = rbase + i * 16 + r;
                    if (grow >= M) continue;
                    atomicAdd((float*)Cp + (size_t)grow * g.ldc + cbase + j * 16, acc[i][j][r]);
                }
    } else if constexpr (MODE == 6) {
        #pragma unroll
        for (int i = 0; i < 4; ++i)
            #pragma unroll
            for (int r = 0; r < 4; ++r) {
                float s = 0.f;
                #pragma unroll
                for (int j = 0; j < 4; ++j) {
                    int gcol = cbase + j * 16;
                    s += fmaxf(acc[i][j][r] + biasp[gcol], 0.f) * g.aux1[gcol];
                }
                s += __shfl_xor(s, 1); s += __shfl_xor(s, 2);
                s += __shfl_xor(s, 4); s += __shfl_xor(s, 8);
                if ((lane & 15) == 0)
                    atomicAdd((float*)Cp + rbase + i * 16 + r, s);
            }
    } else if constexpr (MODE == 9) {
        int grp = tileN >> 10;
        int lcb = (tileN & 1023) + wc + (lane & 15);
        #pragma unroll
        for (int i = 0; i < 4; ++i)
            #pragma unroll
            for (int j = 0; j < 4; ++j)
                #pragma unroll
                for (int r = 0; r < 4; ++r) {
                    int p    = rbase + i * 16 + r;
                    int lcol = lcb + j * 16;
                    float accv = acc[i][j][r];
                    if (grp == 0) {
                        bf16 a2b = __float2bfloat16(accv + g.cb0[lcol]);
                        ((bf16*)Cp)[(size_t)p * 1024 + lcol] = a2b;
                        float a1 = g.Ahp[((size_t)(p >> 8)) * 3072 + lcol]
                                 + g.Aop[((size_t)(p & 255)) * 3072 + lcol] + g.b1p[lcol];
                        ((bf16*)g.dstH)[(size_t)p * 1024 + lcol] =
                            __float2bfloat16(fmaxf(a1 * (float)a2b, 0.f));
                    } else if (grp == 1) {
                        ((bf16*)g.dst1)[(size_t)p * 1024 + lcol] =
                            __float2bfloat16(accv + g.cb1[lcol]);
                    } else if (grp == 2) {
                        ((bf16*)g.dst2)[(size_t)p * 1024 + lcol] =
                            __float2bfloat16(accv + g.cb2[lcol]);
                    } else {
                        float a2v = accv + g.cb3[lcol];
                        ((bf16*)g.dst3)[(size_t)p * 1024 + lcol] =
                            __float2bfloat16(fmaxf(g.a1gv[lcol] * a2v, 0.f));
                    }
                }
    }
}

static GArgs mkargs(const bf16* A, const bf16* B, void* C, const float* bias,
                    const float* aux1, int M, int N, int K, int ldc, int kchunk)
{
    GArgs g{};
    g.A = A; g.B = B; g.C = C; g.bias = bias; g.aux1 = aux1;
    g.M = M; g.N = N; g.K = K; g.ldc = ldc; g.kchunk = kchunk;
    return g;
}

// ---------------------------------------------------------------- reductions over H
// HredH[h,c] = sum_n sh[h,n] * relu((a1[n,c]+b1[c]) * a2[(h*256+n),c]), a1 ld=3072
__global__ void reduce_o2s(const bf16* __restrict__ a2, const float* __restrict__ a1,
                           const float* __restrict__ b1, const float* __restrict__ sh,
                           bf16* __restrict__ out)
{
    int h = blockIdx.y, cq = blockIdx.x;
    int ng = threadIdx.x >> 5, ct = threadIdx.x & 31;
    int c = cq * 256 + ct * 8;
    float b1v[8], accv[8] = {};
    #pragma unroll
    for (int j = 0; j < 8; ++j) b1v[j] = b1[c + j];
    const float* shh = sh + h * 256;
    for (int n = ng; n < 256; n += 8) {
        float w = shh[n];
        bf16x8 a2v = *(const bf16x8*)(a2 + ((size_t)(h * 256 + n) << 10) + c);
        const float* a1p = a1 + (size_t)n * 3072 + c;
        #pragma unroll
        for (int j = 0; j < 8; ++j)
            accv[j] += w * fmaxf((a1p[j] + b1v[j]) * (float)a2v[j], 0.f);
    }
    __shared__ float red[8][264];
    #pragma unroll
    for (int j = 0; j < 8; ++j) red[ng][ct * 8 + j] = accv[j];
    __syncthreads();
    for (int s = 4; s > 0; s >>= 1) {
        if (ng < s)
            #pragma unroll
            for (int j = 0; j < 8; ++j) red[ng][ct * 8 + j] += red[ng + s][ct * 8 + j];
        __syncthreads();
    }
    if (ng == 0) {
        bf16x8 o;
        #pragma unroll
        for (int j = 0; j < 8; ++j) o[j] = (__bf16)red[0][ct * 8 + j];
        *(bf16x8*)(out + (size_t)h * 1024 + c) = o;
    }
}

// HredO[n,c] = sum_h so[n,h] * relu((a1[h,c]+b1[c]) * a2[(h*256+n),c]), a1 ld=2048
__global__ void reduce_s2o(const bf16* __restrict__ a2, const float* __restrict__ a1,
                           const float* __restrict__ b1, const float* __restrict__ so,
                           bf16* __restrict__ out)
{
    int n = blockIdx.y, cq = blockIdx.x;
    int hg = threadIdx.x >> 5, ct = threadIdx.x & 31;
    int c = cq * 256 + ct * 8;
    float b1v[8], accv[8] = {};
    #pragma unroll
    for (int j = 0; j < 8; ++j) b1v[j] = b1[c + j];
    const float* son = so + n * 64;
    #pragma unroll
    for (int hh = 0; hh < 8; ++hh) {
        int h = hg + hh * 8;
        float w = son[h];
        bf16x8 a2v = *(const bf16x8*)(a2 + ((size_t)(h * 256 + n) << 10) + c);
        const float* a1p = a1 + (size_t)h * 2048 + c;
        #pragma unroll
        for (int j = 0; j < 8; ++j)
            accv[j] += w * fmaxf((a1p[j] + b1v[j]) * (float)a2v[j], 0.f);
    }
    __shared__ float red[8][264];
    #pragma unroll
    for (int j = 0; j < 8; ++j) red[hg][ct * 8 + j] = accv[j];
    __syncthreads();
    for (int s = 4; s > 0; s >>= 1) {
        if (hg < s)
            #pragma unroll
            for (int j = 0; j < 8; ++j) red[hg][ct * 8 + j] += red[hg + s][ct * 8 + j];
        __syncthreads();
    }
    if (hg == 0) {
        bf16x8 o;
        #pragma unroll
        for (int j = 0; j < 8; ++j) o[j] = (__bf16)red[0][ct * 8 + j];
        *(bf16x8*)(out + (size_t)n * 1024 + c) = o;
    }
}

// ---------------------------------------------------------------- transposes
__global__ void transp(const float* __restrict__ src, bf16* __restrict__ dst,
                       int rows, int cols, size_t sstride, size_t dstride)
{
    const float* s = src + blockIdx.z * sstride;
    bf16*        d = dst + blockIdx.z * dstride;
    __shared__ float tile[32][33];
    int c0 = blockIdx.x * 32, r0 = blockIdx.y * 32;
    int x = threadIdx.x, y = threadIdx.y;   // (32, 8)
    for (int yy = y; yy < 32; yy += 8) {
        int r = r0 + yy, c = c0 + x;
        tile[yy][x] = (r < rows && c < cols) ? s[(size_t)r * cols + c] : 0.f;
    }
    __syncthreads();
    for (int yy = y; yy < 32; yy += 8) {
        int c = c0 + yy, r = r0 + x;
        if (c < cols && r < rows) d[(size_t)c * rows + r] = __float2bfloat16(tile[x][yy]);
    }
}

struct T9 { const float* s[9]; bf16* d[9]; size_t ss[9]; };
// 9 weights, each 16 z-slices of 1024x64 -> 64x1024; grid (2, 32, 144)
__global__ void transp64b(T9 t)
{
    int pair = blockIdx.z >> 4, slice = blockIdx.z & 15;
    const float* s = t.s[pair] + slice * t.ss[pair];
    bf16*        d = t.d[pair] + slice * 65536;
    __shared__ float tile[32][33];
    int c0 = blockIdx.x * 32, r0 = blockIdx.y * 32;
    int x = threadIdx.x, y = threadIdx.y;
    for (int yy = y; yy < 32; yy += 8)
        tile[yy][x] = s[(size_t)(r0 + yy) * 64 + c0 + x];
    __syncthreads();
    for (int yy = y; yy < 32; yy += 8)
        d[(size_t)(c0 + yy) * 1024 + r0 + x] = __float2bfloat16(tile[x][yy]);
}

struct T4 { const float* s[4]; bf16* d[4]; };
__global__ void transp1024b(T4 t)
{
    const float* s = t.s[blockIdx.z];
    bf16*        d = t.d[blockIdx.z];
    __shared__ float tile[32][33];
    int c0 = blockIdx.x * 32, r0 = blockIdx.y * 32;
    int x = threadIdx.x, y = threadIdx.y;
    for (int yy = y; yy < 32; yy += 8)
        tile[yy][x] = s[(size_t)(r0 + yy) * 1024 + c0 + x];
    __syncthreads();
    for (int yy = y; yy < 32; yy += 8)
        d[(size_t)(c0 + yy) * 1024 + r0 + x] = __float2bfloat16(tile[x][yy]);
}

__global__ void conv_spw1(const float* __restrict__ src, bf16* __restrict__ dst) {
    int i = blockIdx.x * 256 + threadIdx.x;
    if (i >= 128 * 64) return;
    int k = i & 63, n = i >> 6;
    dst[i] = __float2bfloat16(k < 36 ? src[k * 128 + n] : 0.f);
}

__global__ void pad_spatial(const float* __restrict__ src, bf16* __restrict__ dst) {
    int i = blockIdx.x * 256 + threadIdx.x;
    int k = i & 63, p = i >> 6;
    dst[i] = __float2bfloat16(k < 36 ? src[p * 36 + k] : 0.f);
}

__global__ void cast_f2b(const float* __restrict__ src, bf16* __restrict__ dst, int n) {
    int i = blockIdx.x * 256 + threadIdx.x;
    if (i < n) dst[i] = __float2bfloat16(src[i]);
}

struct S4 { const float* s[4]; float* d[4]; };
__global__ void sumb3b(S4 a) {
    int i = blockIdx.x * 256 + threadIdx.x;
    int pair = i >> 10, r = i & 1023;
    const float* b3 = a.s[pair];
    float s = 0.f;
    #pragma unroll
    for (int c = 0; c < 16; ++c) s += b3[c * 1024 + r];
    a.d[pair][r] = s;
}

// H = relu((Ah[p>>8] + Ao[p&255] + b1) * a2)
__global__ void hbuild(const float* __restrict__ Ah, int ah_ld,
                       const float* __restrict__ Ao, int ao_ld,
                       const float* __restrict__ b1, const bf16* __restrict__ a2,
                       bf16* __restrict__ H)
{
    size_t base = ((size_t)blockIdx.x * 256 + threadIdx.x) * 8;
    int cs = (int)(base & 1023);
    int p  = (int)(base >> 10);
    const float* ph = Ah + (size_t)(p >> 8) * ah_ld + cs;
    const float* po = Ao + (size_t)(p & 255) * ao_ld + cs;
    bf16x8 av = *(const bf16x8*)(a2 + base);
    bf16x8 o;
    #pragma unroll
    for (int j = 0; j < 8; ++j) {
        float a1 = ph[j] + po[j] + b1[cs + j];
        o[j] = (__bf16)fmaxf(a1 * (float)av[j], 0.f);
    }
    *(bf16x8*)(H + base) = o;
}

// ---------------------------------------------------------------- softmax / LN
__global__ void softmax_h(const float* __restrict__ adj, float* __restrict__ sh) {
    int h = blockIdx.x, n = threadIdx.x;
    __shared__ float red[256];
    float v = adj[h * 256 + n];
    red[n] = v; __syncthreads();
    for (int s = 128; s > 0; s >>= 1) { if (n < s) red[n] = fmaxf(red[n], red[n + s]); __syncthreads(); }
    float m = red[0]; __syncthreads();
    float e = expf(v - m);
    red[n] = e; __syncthreads();
    for (int s = 128; s > 0; s >>= 1) { if (n < s) red[n] += red[n + s]; __syncthreads(); }
    sh[h * 256 + n] = e / red[0];
}

__global__ void softmax_o(const float* __restrict__ adj, float* __restrict__ so) {
    int n = blockIdx.x, h = threadIdx.x;
    float v = adj[h * 256 + n];
    float m = v;
    #pragma unroll
    for (int off = 32; off; off >>= 1) m = fmaxf(m, __shfl_xor(m, off));
    float e = expf(v - m);
    float s = e;
    #pragma unroll
    for (int off = 32; off; off >>= 1) s += __shfl_xor(s, off);
    so[n * 64 + h] = e / s;
}

__global__ void ln_k(const float* __restrict__ x, const float* __restrict__ msgraw,
                     const float* __restrict__ sb3,
                     const float* __restrict__ g, const float* __restrict__ bb,
                     bf16* __restrict__ out)
{
    int row = blockIdx.x, t = threadIdx.x;
    const float* xr = x + (size_t)row * 1024;
    const float* mr = msgraw + (size_t)row * 1024;
    float v[4]; float s = 0.f, ss = 0.f;
    #pragma unroll
    for (int j = 0; j < 4; ++j) {
        int i = t + j * 256;
        v[j] = xr[i] + fmaxf(mr[i] + sb3[i], 0.f);
        s += v[j]; ss += v[j] * v[j];
    }
    __shared__ float r1[256], r2[256];
    r1[t] = s; r2[t] = ss; __syncthreads();
    for (int k = 128; k > 0; k >>= 1) { if (t < k) { r1[t] += r1[t + k]; r2[t] += r2[t + k]; } __syncthreads(); }
    float mean = r1[0] * (1.f / 1024.f);
    float var  = r2[0] * (1.f / 1024.f) - mean * mean;
    float inv  = rsqrtf(var + 1e-5f);
    #pragma unroll
    for (int j = 0; j < 4; ++j) {
        int i = t + j * 256;
        out[(size_t)row * 1024 + i] = __float2bfloat16((v[j] - mean) * inv * g[i] + bb[i]);
    }
}

__global__ void a1g_k(const float* __restrict__ gf, const float* __restrict__ W1,
                      const float* __restrict__ b1, float* __restrict__ a1g)
{
    int cs = blockIdx.x * 256 + threadIdx.x;
    int c = cs >> 6, s = cs & 63;
    float acc = b1[cs];
    for (int g = 0; g < 256; ++g) acc += gf[g] * W1[((size_t)c * 256 + g) * 64 + s];
    a1g[cs] = acc;
}

// ---------------------------------------------------------------- launch
extern "C" void kernel_launch(void* const* d_in, const int* in_sizes, int n_in,
                              void* d_out, int out_size, void* d_ws, size_t ws_size,
                              hipStream_t stream)
{
    const float* node_enc = (const float*)d_in[0];
    const float* spatial  = (const float*)d_in[1];
    const float* gfeat    = (const float*)d_in[2];
    const float* sp_W1 = (const float*)d_in[3];  const float* sp_b1 = (const float*)d_in[4];
    const float* sp_W2 = (const float*)d_in[5];  const float* sp_b2 = (const float*)d_in[6];
    const float* sp_W3 = (const float*)d_in[7];  const float* sp_b3 = (const float*)d_in[8];
    const float* ah_W1 = (const float*)d_in[9];  const float* ah_b1 = (const float*)d_in[10];
    const float* ah_W2 = (const float*)d_in[11]; const float* ah_b2 = (const float*)d_in[12];
    const float* ah_W3 = (const float*)d_in[13]; const float* ah_b3 = (const float*)d_in[14];
    const float* o2s_W1 = (const float*)d_in[15]; const float* o2s_b1 = (const float*)d_in[16];
    const float* o2s_W2 = (const float*)d_in[17]; const float* o2s_b2 = (const float*)d_in[18];
    const float* o2s_W3 = (const float*)d_in[19]; const float* o2s_b3 = (const float*)d_in[20];
    const float* s2o_W1 = (const float*)d_in[21]; const float* s2o_b1 = (const float*)d_in[22];
    const float* s2o_W2 = (const float*)d_in[23]; const float* s2o_b2 = (const float*)d_in[24];
    const float* s2o_W3 = (const float*)d_in[25]; const float* s2o_b3 = (const float*)d_in[26];
    const float* ahg_W1 = (const float*)d_in[27]; const float* ahg_b1 = (const float*)d_in[28];
    const float* ahg_W2 = (const float*)d_in[29]; const float* ahg_b2 = (const float*)d_in[30];
    const float* ahg_W3 = (const float*)d_in[31]; const float* ahg_b3 = (const float*)d_in[32];
    const float* adj_W = (const float*)d_in[33];
    const float* lnh_g = (const float*)d_in[35]; const float* lnh_b = (const float*)d_in[36];
    const float* lno_g = (const float*)d_in[37]; const float* lno_b = (const float*)d_in[38];

    char* w = (char*)d_ws;
    auto alloc = [&](size_t bytes) { char* p = w; w += (bytes + 255) & ~(size_t)255; return p; };
    bf16*  sp      = (bf16*)alloc((size_t)P_ * 1024 * 2);
    bf16*  a2_ah   = (bf16*)alloc((size_t)P_ * 1024 * 2);
    bf16*  Hbuf    = (bf16*)alloc((size_t)P_ * 1024 * 2);
    bf16*  a2_o2s  = (bf16*)alloc((size_t)P_ * 1024 * 2);
    bf16*  a2_s2o  = (bf16*)alloc((size_t)P_ * 1024 * 2);
    bf16*  H_ahg   = (bf16*)alloc((size_t)P_ * 1024 * 2);
    bf16*  spat_pad= (bf16*)alloc((size_t)P_ * 64 * 2);
    bf16*  spL1    = (bf16*)alloc((size_t)P_ * 128 * 2);
    bf16*  spL2    = (bf16*)alloc((size_t)P_ * 256 * 2);
    bf16*  enc_bf  = (bf16*)alloc(256 * 1024 * 2);
    bf16*  henc_bf = (bf16*)alloc(64 * 1024 * 2);
    bf16*  oenc_bf = (bf16*)alloc(256 * 1024 * 2);
    bf16*  HredH   = (bf16*)alloc(64 * 1024 * 2);
    bf16*  HredO   = (bf16*)alloc(256 * 1024 * 2);
    bf16*  spW1t   = (bf16*)alloc(128 * 64 * 2);
    bf16*  spW2t   = (bf16*)alloc(256 * 128 * 2);
    bf16*  spW3t   = (bf16*)alloc(1024 * 256 * 2);
    bf16*  W2cat   = (bf16*)alloc((size_t)4096 * 1024 * 2); // [ah; o2s; s2o; ahg]
    bf16*  W1cat3  = (bf16*)alloc((size_t)3072 * 1024 * 2); // [ahW1tB; o2sW1t; ahW1tT]
    bf16*  W1catF  = (bf16*)alloc((size_t)2048 * 1024 * 2); // [s2oW1t; ahW1tT]
    bf16*  ahW3t   = (bf16*)alloc(1024 * 1024 * 2);
    bf16*  o2sW3t  = (bf16*)alloc(1024 * 1024 * 2);
    bf16*  s2oW3t  = (bf16*)alloc(1024 * 1024 * 2);
    bf16*  ahgW3t  = (bf16*)alloc(1024 * 1024 * 2);
    // zero-init block 1: Aoa1x | A1f | Ao_f
    float* Aoa1x = (float*)alloc(256 * 3072 * 4);   // cols: Ao | a1o2s | Ah(rows<64)
    float* A1f   = (float*)alloc(64 * 2048 * 4);    // cols: a1s2o | Ah_f
    float* Ao_f  = (float*)alloc(256 * 1024 * 4);
    size_t z1_bytes = (size_t)(256 * 3072 + 64 * 2048 + 256 * 1024) * 4 + 1024;
    // zero-init block 2: adjv | msgh | msgo
    float* adjv  = (float*)alloc(P_ * 4);
    float* msgh  = (float*)alloc(64 * 1024 * 4);
    float* msgo  = (float*)alloc(256 * 1024 * 4);
    size_t z2_bytes = (size_t)(P_ + 64 * 1024 + 256 * 1024) * 4 + 1024;
    float* sh    = (float*)alloc(P_ * 4);
    float* so    = (float*)alloc(P_ * 4);
    float* a1g   = (float*)alloc(1024 * 4);
    float* sb3_ah  = (float*)alloc(4096);
    float* sb3_o2s = (float*)alloc(4096);
    float* sb3_s2o = (float*)alloc(4096);
    float* sb3_ahg = (float*)alloc(4096);

    hipMemsetAsync(Aoa1x, 0, z1_bytes, stream);
    hipMemsetAsync(adjv,  0, z2_bytes, stream);

    // ---- batched weight conversions
    {
        T9 t;
        t.s[0] = ah_W1;                     t.d[0] = W1cat3 + (size_t)2048 * 1024; t.ss[0] = (size_t)2048 * 64; // ahT
        t.s[1] = ah_W1 + (size_t)1024 * 64; t.d[1] = W1cat3;                       t.ss[1] = (size_t)2048 * 64; // ahB
        t.s[2] = o2s_W1;                    t.d[2] = W1cat3 + (size_t)1024 * 1024; t.ss[2] = 65536;
        t.s[3] = s2o_W1;                    t.d[3] = W1catF;                       t.ss[3] = 65536;
        t.s[4] = ah_W1;                     t.d[4] = W1catF + (size_t)1024 * 1024; t.ss[4] = (size_t)2048 * 64; // ahT copy
        t.s[5] = ah_W2;                     t.d[5] = W2cat;                        t.ss[5] = 65536;
        t.s[6] = o2s_W2;                    t.d[6] = W2cat + (size_t)1024 * 1024;  t.ss[6] = 65536;
        t.s[7] = s2o_W2;                    t.d[7] = W2cat + (size_t)2048 * 1024;  t.ss[7] = 65536;
        t.s[8] = ahg_W2;                    t.d[8] = W2cat + (size_t)3072 * 1024;  t.ss[8] = 65536;
        transp64b<<<dim3(2, 32, 144), dim3(32, 8), 0, stream>>>(t);
    }
    {
        T4 t;
        t.s[0] = ah_W3;  t.d[0] = ahW3t;
        t.s[1] = o2s_W3; t.d[1] = o2sW3t;
        t.s[2] = s2o_W3; t.d[2] = s2oW3t;
        t.s[3] = ahg_W3; t.d[3] = ahgW3t;
        transp1024b<<<dim3(32, 32, 4), dim3(32, 8), 0, stream>>>(t);
    }
    dim3 tb(32, 8);
    conv_spw1<<<32, 256, 0, stream>>>(sp_W1, spW1t);
    transp<<<dim3(8, 4, 1),  tb, 0, stream>>>(sp_W2, spW2t, 128, 256, 0, 0);
    transp<<<dim3(32, 8, 1), tb, 0, stream>>>(sp_W3, spW3t, 256, 1024, 0, 0);
    pad_spatial<<<4096, 256, 0, stream>>>(spatial, spat_pad);
    cast_f2b<<<1024, 256, 0, stream>>>(node_enc, enc_bf, 256 * 1024);
    {
        S4 a;
        a.s[0] = ah_b3;  a.d[0] = sb3_ah;
        a.s[1] = o2s_b3; a.d[1] = sb3_o2s;
        a.s[2] = s2o_b3; a.d[2] = sb3_s2o;
        a.s[3] = ahg_b3; a.d[3] = sb3_ahg;
        sumb3b<<<16, 256, 0, stream>>>(a);
    }
    a1g_k<<<4, 256, 0, stream>>>(gfeat, ahg_W1, ahg_b1, a1g);

    // ---- W1 split-K GEMM: enc @ [ahB | o2s | ahT] -> Aoa1x (256 x 3072)
    gemm_bt<2, false, false><<<dim3(2, 24, 16), 256, 0, stream>>>(
        mkargs(enc_bf, W1cat3, Aoa1x, nullptr, nullptr, 256, 3072, 1024, 3072, 64));

    // ---- sp MLP
    gemm_bt<1, true, true><<<dim3(128, 1), 256, 0, stream>>>(
        mkargs(spat_pad, spW1t, spL1, sp_b1, nullptr, P_, 128, 64, 128, 0));
    gemm_bt<1, true, true><<<dim3(128, 2), 256, 0, stream>>>(
        mkargs(spL1, spW2t, spL2, sp_b2, nullptr, P_, 256, 128, 256, 0));
    gemm_bt<1, true, true><<<dim3(128, 8), 256, 0, stream>>>(
        mkargs(spL2, spW3t, sp, sp_b3, nullptr, P_, 1024, 256, 1024, 0));

    // ---- merged W2 GEMM: N=4096 -> a2_ah+Hbuf | a2_o2s | a2_s2o | H_ahg
    {
        GArgs g = mkargs(sp, W2cat, a2_ah, nullptr, nullptr, P_, 4096, 1024, 1024, 0);
        g.dst1 = a2_o2s; g.dst2 = a2_s2o; g.dst3 = H_ahg; g.dstH = Hbuf;
        g.cb0 = ah_b2; g.cb1 = o2s_b2; g.cb2 = s2o_b2; g.cb3 = ahg_b2;
        g.a1gv = a1g; g.Ahp = Aoa1x + 2048; g.Aop = Aoa1x; g.b1p = ah_b1;
        gemm_bt<9, false, false><<<dim3(128, 32), 256, 0, stream>>>(g);
    }

    // ---- adj -> softmaxes
    gemm_bt<6, false, false><<<dim3(128, 8), 256, 0, stream>>>(
        mkargs(Hbuf, ahW3t, adjv, sb3_ah, adj_W, P_, 1024, 1024, 1024, 0));
    softmax_h<<<64, 256, 0, stream>>>(adjv, sh);
    softmax_o<<<256, 64, 0, stream>>>(adjv, so);

    // ---- msg_h = Hred_h @ o2sW3 -> h_enc'
    reduce_o2s<<<dim3(4, 64), 256, 0, stream>>>(a2_o2s, Aoa1x + 1024, o2s_b1, sh, HredH);
    gemm_bt<2, false, false><<<dim3(1, 8, 16), 256, 0, stream>>>(
        mkargs(HredH, o2sW3t, msgh, nullptr, nullptr, 64, 1024, 1024, 1024, 64));
    ln_k<<<64, 256, 0, stream>>>(node_enc, msgh, sb3_o2s, lnh_g, lnh_b, henc_bf);

    // ---- {a1s2o | Ah_f}
    gemm_bt<2, false, false><<<dim3(1, 16, 16), 256, 0, stream>>>(
        mkargs(henc_bf, W1catF, A1f, nullptr, nullptr, 64, 2048, 1024, 2048, 64));

    // ---- msg_o = Hred_o @ s2oW3 -> o_enc'
    reduce_s2o<<<dim3(4, 256), 256, 0, stream>>>(a2_s2o, A1f, s2o_b1, so, HredO);
    gemm_bt<2, false, false><<<dim3(2, 8, 16), 256, 0, stream>>>(
        mkargs(HredO, s2oW3t, msgo, nullptr, nullptr, 256, 1024, 1024, 1024, 64));
    ln_k<<<256, 256, 0, stream>>>(node_enc, msgo, sb3_s2o, lno_g, lno_b, oenc_bf);

    // ---- Ao_f, final ah-head H
    gemm_bt<2, false, false><<<dim3(2, 8, 16), 256, 0, stream>>>(
        mkargs(oenc_bf, W1cat3, Ao_f, nullptr, nullptr, 256, 1024, 1024, 1024, 64));
    hbuild<<<8192, 256, 0, stream>>>(A1f + 1024, 2048, Ao_f, 1024, ah_b1, a2_ah, Hbuf);

    // ---- f_local (z=0) + f_glob (z=1) in one dispatch
    {
        GArgs g = mkargs(Hbuf, ahW3t, (float*)d_out, sb3_ah, nullptr, P_, 1024, 1024, 2048, 0);
        g.dst1 = (void*)H_ahg; g.dst2 = (void*)ahgW3t;
        g.dst3 = (void*)((float*)d_out + 1024); g.cb1 = sb3_ahg;
        gemm_bt<0, true, true><<<dim3(128, 8, 2), 256, 0, stream>>>(g);
    }

    (void)in_sizes; (void)n_in; (void)out_size; (void)ws_size;
}